// Round 4
// baseline (758.210 us; speedup 1.0000x reference)
//
#include <hip/hip_runtime.h>
#include <cstdint>
#include <cstddef>

#define DIM 256
#define NH 4
#define W 8
#define SCALE 0.125f

typedef __bf16 bf16x8 __attribute__((ext_vector_type(8)));
typedef float f32x4 __attribute__((ext_vector_type(4)));
typedef float f32x16 __attribute__((ext_vector_type(16)));

__device__ __forceinline__ f32x4 ld4(const float* p) { return *(const f32x4*)p; }
__device__ __forceinline__ f32x4 ld4_nt(const float* p) {
  return __builtin_nontemporal_load((const f32x4*)p);
}
__device__ __forceinline__ unsigned short f2b(float f) {
  __bf16 b = (__bf16)f;
  return __builtin_bit_cast(unsigned short, b);
}

// ---------------------------------------------------------------------------
// Precompute 1: Astack = [SCALE * Wq_n^T Wk_n]_n stacked to (256 k x 1024 col),
// bf16, MFMA-B-fragment layout: [kt 8][nt 64][lane 64][j 8],
// k = kt*32 + (lane>>4)*8 + j, col = nt*16 + (lane&15). LDS-staged operands.
// ---------------------------------------------------------------------------
__global__ void precomp_a(const float* __restrict__ Wq, const float* __restrict__ Wk,
                          unsigned short* __restrict__ Asw) {
  __shared__ float q_s[64][32];
  __shared__ float k_s[64][16];
  int blk = blockIdx.x;              // kt*64 + nt   (512 blocks)
  int kt = blk >> 6, nt = blk & 63;
  int n = nt >> 4;                   // head (col range nt*16.. stays in one head)
  int tid = threadIdx.x;
  for (int i = tid; i < 2048; i += 256) {
    int d = i >> 5, k = i & 31;
    q_s[d][k] = Wq[(n * 64 + d) * 256 + kt * 32 + k];
  }
  for (int i = tid; i < 1024; i += 256) {
    int d = i >> 4, b = i & 15;
    k_s[d][b] = Wk[(n * 64 + d) * 256 + (nt & 15) * 16 + b];
  }
  __syncthreads();
  for (int x = tid; x < 512; x += 256) {
    int lane = x & 63, j = x >> 6;
    int kl = ((lane >> 4) * 8) + j;   // local k 0..31
    int c = lane & 15;                // local col 0..15
    float s = 0.f;
#pragma unroll 8
    for (int d = 0; d < 64; ++d) s += q_s[d][kl] * k_s[d][c];
    Asw[(size_t)blk * 512 + (size_t)lane * 8 + j] = f2b(s * SCALE);
  }
}

// ---------------------------------------------------------------------------
// Precompute 2: u_stack (f32), Bvsw (bf16 swizzled bias-dot cols), gu table
// (bf16, 2 records x [ks16][hi2][slot4][j8]; rec0 slots = wvo heads, rec1
// slot0 = Wu, rest 0), consts s[4], c0.
// ---------------------------------------------------------------------------
__global__ void precomp_b(const float* __restrict__ Wq, const float* __restrict__ Wk,
                          const float* __restrict__ Wv, const float* __restrict__ bq,
                          const float* __restrict__ bk, const float* __restrict__ bv,
                          const float* __restrict__ Wo, const float* __restrict__ bo,
                          const float* __restrict__ Wu,
                          unsigned short* __restrict__ Bvsw, float* __restrict__ u_stack,
                          unsigned short* __restrict__ gu, float* __restrict__ consts) {
  __shared__ float v_s[1024];
  __shared__ float w_s[1024];
  int t = threadIdx.x;
  for (int col = t; col < 1024; col += 256) {
    int n = col >> 8, b = col & 255;
    float su = 0.f, sw = 0.f, sv = 0.f;
#pragma unroll 8
    for (int d = 0; d < 64; ++d) {
      float wkv = Wk[(n * 64 + d) * 256 + b];
      su += bq[n * 64 + d] * wkv;
      sw += Wv[(n * 64 + d) * 256 + b] * Wo[n * 64 + d];
      sv += Wq[(n * 64 + d) * 256 + b] * bk[n * 64 + d];
    }
    u_stack[col] = su * SCALE;
    w_s[col] = sw;
    v_s[col] = sv * SCALE;
  }
  __syncthreads();
  for (int x = t; x < 8 * 64 * 8; x += 256) {   // Bvsw [kt][lane][j]
    int j = x & 7, lane = (x >> 3) & 63, kt = x >> 9;
    int colc = lane & 15;
    int k = kt * 32 + ((lane >> 4) * 8) + j;
    unsigned short val = 0;
    if (colc < 4) val = f2b(v_s[colc * 256 + k]);
    Bvsw[x] = val;
  }
  for (int i = t; i < 2048; i += 256) {          // gu [rec][ks][hi][slot][j]
    int rec = i >> 10, r0 = i & 1023;
    int ks = r0 >> 6, hi = (r0 >> 5) & 1, slot = (r0 >> 3) & 3, j = r0 & 7;
    int k = ks * 16 + hi * 8 + j;
    float val = (rec == 0) ? w_s[slot * 256 + k] : (slot == 0 ? Wu[k] : 0.f);
    gu[i] = f2b(val);
  }
  if (t < 4) {
    float s = 0.f;
    for (int d = 0; d < 64; ++d) s += bq[t * 64 + d] * bk[t * 64 + d];
    consts[t] = s * SCALE;
  }
  if (t == 4) {
    float s = bo[0];
    for (int d = 0; d < 256; ++d) s += bv[d] * Wo[d];
    consts[4] = s;
  }
}

// ---------------------------------------------------------------------------
// Kernel A: T = bf16(h) @ Astack.  M=32 per block (2 M-tiles share each
// B-fragment -> Astack L2 traffic halves). Wave = head. No LDS.
// T stored bf16 fragment-ready: [edge][ks 16][hi 2][head 4][j 8],
// element = t[edge][head*256 + ks*16 + hi*8 + j].
// Also r_g[edge][4] = h . v_n + s_n (bias dots; zero-valued here).
// ---------------------------------------------------------------------------
__global__ __launch_bounds__(256, 2) void proj_t(
    const float* __restrict__ h_i, const unsigned short* __restrict__ Asw,
    const unsigned short* __restrict__ Bvsw, const float* __restrict__ u_stack,
    const float* __restrict__ consts,
    unsigned short* __restrict__ Tsw, float* __restrict__ r_g) {
  const int tid = threadIdx.x;
  const int wid = tid >> 6;        // head
  const int lane = tid & 63;
  const int e0 = blockIdx.x * 32;
  const int row = lane & 15, kg = lane >> 4;

  f32x4 zero4 = {0.f, 0.f, 0.f, 0.f};
  f32x4 acc0[16], acc1[16];
#pragma unroll
  for (int i = 0; i < 16; ++i) { acc0[i] = zero4; acc1[i] = zero4; }
  f32x4 accr0 = zero4, accr1 = zero4;

  const float* hrow0 = h_i + (size_t)(e0 + row) * DIM + kg * 8;
  const float* hrow1 = h_i + (size_t)(e0 + 16 + row) * DIM + kg * 8;
  const bf16x8* asw_b = (const bf16x8*)Asw;
  const bf16x8* bv_b = (const bf16x8*)Bvsw;

#pragma unroll
  for (int ks = 0; ks < 8; ++ks) {
    f32x4 a0 = ld4(hrow0 + ks * 32), a1 = ld4(hrow0 + ks * 32 + 4);
    f32x4 b0 = ld4(hrow1 + ks * 32), b1 = ld4(hrow1 + ks * 32 + 4);
    bf16x8 af0, af1;
#pragma unroll
    for (int j = 0; j < 4; ++j) {
      af0[j] = (__bf16)a0[j]; af0[j + 4] = (__bf16)a1[j];
      af1[j] = (__bf16)b0[j]; af1[j + 4] = (__bf16)b1[j];
    }
    const bf16x8* bb = asw_b + (size_t)(ks * 64 + wid * 16) * 64 + lane;
#pragma unroll
    for (int nt = 0; nt < 16; ++nt) {
      bf16x8 bf = bb[(size_t)nt * 64];
      acc0[nt] = __builtin_amdgcn_mfma_f32_16x16x32_bf16(af0, bf, acc0[nt], 0, 0, 0);
      acc1[nt] = __builtin_amdgcn_mfma_f32_16x16x32_bf16(af1, bf, acc1[nt], 0, 0, 0);
    }
    if (wid == 0) {
      bf16x8 bvf = bv_b[ks * 64 + lane];
      accr0 = __builtin_amdgcn_mfma_f32_16x16x32_bf16(af0, bvf, accr0, 0, 0, 0);
      accr1 = __builtin_amdgcn_mfma_f32_16x16x32_bf16(af1, bvf, accr1, 0, 0, 0);
    }
  }
  // D layout: edge = kg*4 + r, head-local dim k = nt*16 + row
  // store offset = edge*1024 + nt*64 + (row>>3)*32 + wid*8 + (row&7)
#pragma unroll
  for (int nt = 0; nt < 16; ++nt) {
    float uv = u_stack[wid * 256 + nt * 16 + row];
    unsigned off = nt * 64 + ((row >> 3) * 32) + wid * 8 + (row & 7);
#pragma unroll
    for (int r = 0; r < 4; ++r) {
      Tsw[(size_t)(e0 + kg * 4 + r) * 1024 + off] = f2b(acc0[nt][r] + uv);
      Tsw[(size_t)(e0 + 16 + kg * 4 + r) * 1024 + off] = f2b(acc1[nt][r] + uv);
    }
  }
  if (wid == 0 && row < 4) {
    float sv = consts[row];
#pragma unroll
    for (int r = 0; r < 4; ++r) {
      r_g[(size_t)(e0 + kg * 4 + r) * 4 + row] = accr0[r] + sv;
      r_g[(size_t)(e0 + 16 + kg * 4 + r) * 4 + row] = accr1[r] + sv;
    }
  }
}

// ---------------------------------------------------------------------------
// Kernel B: per-edge epilogue. Block = 16 edges, wave owns 4 edges end-to-end.
// One 32x32x16 bf16 MFMA chain per wave: A rows = 4 edges x 8 windows of evol
// (software-pipelined 2-ahead from global), B cols = 4x4 T-heads | wvo x4 |
// Wu | zeros (T/gu direct per-lane 16B global loads, no LDS). Then softmax +
// head combine + conf + sigmoid, exactly as before.
// ---------------------------------------------------------------------------
__global__ __launch_bounds__(256, 4) void edge_epi(
    const float* __restrict__ evol, const float* __restrict__ evt,
    const float* __restrict__ var_i, const float* __restrict__ var_j,
    const float* __restrict__ cur_t, const float* __restrict__ tdp,
    const float* __restrict__ bup, const unsigned short* __restrict__ Tsw,
    const unsigned short* __restrict__ gu, const float* __restrict__ r_g,
    const float* __restrict__ consts, float* __restrict__ out) {

  __shared__ float bounce[NH][5][32];
  __shared__ float conf_lds[NH][4];

  const int tid = threadIdx.x;
  const int wid = tid >> 6;
  const int lane = tid & 63;
  const int e0 = blockIdx.x * 16;
  const int eb = e0 + wid * 4;

  const int col = lane & 31, hi = lane >> 5;
  const int be = col >> 2, bn = col & 3;   // B: local edge, head (col<16)
  const int ae = col >> 3, aw = col & 7;   // A: local edge, window

  const float* evrow = evol + (size_t)(eb + ae) * (W * DIM) + aw * DIM + hi * 8;
  const unsigned short* bptr =
      (col < 16) ? Tsw + (size_t)(eb + be) * 1024 + bn * 8
                 : gu + (be >= 5 ? 1024 : 0) + bn * 8;

  // epilogue operands issued early (hide under MFMA loop)
  const float tdec = fabsf(tdp[0]);
  const float buv = bup[0];
  const float c0 = consts[4];
  f32x4 et = {0.f, 0.f, 0.f, 0.f};
  float ctv = 0.f, rv = 0.f;
  if (col < 16) {
    et = ld4(evt + (size_t)(eb + be) * W + hi * 4);
    ctv = cur_t[eb + be];
    rv = r_g[(size_t)(eb + be) * 4 + bn];
  }
  const int ve = lane >> 4, vq = lane & 15;
  const float* vip = var_i + (size_t)(eb + ve) * DIM + vq * 16;
  const float* vjp = var_j + (size_t)(eb + ve) * DIM + vq * 16;
  f32x4 vi0 = ld4_nt(vip), vi1 = ld4_nt(vip + 4), vi2 = ld4_nt(vip + 8), vi3 = ld4_nt(vip + 12);
  f32x4 vj0 = ld4_nt(vjp), vj1 = ld4_nt(vjp + 4), vj2 = ld4_nt(vjp + 8), vj3 = ld4_nt(vjp + 12);

  // ---- MFMA dot chain, 16 K-steps, 3-stage (2-ahead) pipeline ----
  f32x4 pa0[3], pa1[3];
  bf16x8 pb[3];
#define ISSUE(st, ks)                                                          \
  {                                                                            \
    pa0[st] = ld4_nt(evrow + (ks) * 16);                                       \
    pa1[st] = ld4_nt(evrow + (ks) * 16 + 4);                                   \
    pb[st] = *(const bf16x8*)(bptr + (ks) * 64 + hi * 32);                     \
  }
  ISSUE(0, 0)
  ISSUE(1, 1)
  f32x16 dacc0 = {0.f}, dacc1 = {0.f};
#pragma unroll
  for (int ks = 0; ks < 16; ++ks) {
    const int st = ks % 3;
    if (ks + 2 < 16) ISSUE((ks + 2) % 3, ks + 2)
    bf16x8 af;
#pragma unroll
    for (int j = 0; j < 4; ++j) {
      af[j] = (__bf16)pa0[st][j];
      af[j + 4] = (__bf16)pa1[st][j];
    }
    if (ks & 1) dacc1 = __builtin_amdgcn_mfma_f32_32x32x16_bf16(af, pb[st], dacc1, 0, 0, 0);
    else        dacc0 = __builtin_amdgcn_mfma_f32_32x32x16_bf16(af, pb[st], dacc0, 0, 0, 0);
  }
#undef ISSUE
  f32x16 d = dacc0 + dacc1;

  // bounce dg (cols 16-19) and du (col 20), indexed by D row = edge*8+window
  if (col >= 16 && col < 21) {
    float* bw = &bounce[wid][col - 16][0];
#pragma unroll
    for (int r = 0; r < 16; ++r)
      bw[(r & 3) + 8 * (r >> 2) + 4 * hi] = d[r];
  }

  float logit_e = 0.f;
  if (col < 16) {
    float s[4] = {0.f, 0.f, 0.f, 0.f};
#pragma unroll
    for (int r = 0; r < 16; ++r)
      s[r & 3] = ((r >> 2) == be) ? d[r] : s[r & 3];

    f32x4 g  = *(const f32x4*)&bounce[wid][bn][be * 8 + hi * 4];
    f32x4 uu = *(const f32x4*)&bounce[wid][4][be * 8 + hi * 4];

    float L[4];
#pragma unroll
    for (int w = 0; w < 4; ++w) {
      float tb = -tdec * fmaxf(ctv - et[w], 0.f);
      float unc = 1.f / (1.f + __expf(-(uu[w] + buv)));
      L[w] = (s[w] + rv + tb) * unc;
    }
    float m4 = fmaxf(fmaxf(L[0], L[1]), fmaxf(L[2], L[3]));
    float mx = fmaxf(m4, __shfl_xor(m4, 32));
    float ps = 0.f, pg = 0.f;
#pragma unroll
    for (int w = 0; w < 4; ++w) {
      float p = __expf(L[w] - mx);
      ps += p; pg += p * g[w];
    }
    ps += __shfl_xor(ps, 32);
    pg += __shfl_xor(pg, 32);
    float part = pg / ps;                 // this head's pooled . Wo_n
    part += __shfl_xor(part, 1);          // sum heads
    part += __shfl_xor(part, 2);
    logit_e = part + c0;
  }

  // conf: per-wave var means (16 lanes per edge)
  float si = vi0[0]+vi0[1]+vi0[2]+vi0[3] + vi1[0]+vi1[1]+vi1[2]+vi1[3]
           + vi2[0]+vi2[1]+vi2[2]+vi2[3] + vi3[0]+vi3[1]+vi3[2]+vi3[3];
  float sj = vj0[0]+vj0[1]+vj0[2]+vj0[3] + vj1[0]+vj1[1]+vj1[2]+vj1[3]
           + vj2[0]+vj2[1]+vj2[2]+vj2[3] + vj3[0]+vj3[1]+vj3[2]+vj3[3];
#pragma unroll
  for (int sft = 1; sft < 16; sft <<= 1) {
    si += __shfl_xor(si, sft);
    sj += __shfl_xor(sj, sft);
  }
  if (vq == 0) {
    float ci = 1.f / (1.f + fmaxf(sqrtf(si * (1.f / 256.f)), 1e-6f));
    float cj = 1.f / (1.f + fmaxf(sqrtf(sj * (1.f / 256.f)), 1e-6f));
    conf_lds[wid][ve] = ci * cj;
  }

  if (col < 16 && bn == 0 && hi == 0) {
    float cf = conf_lds[wid][be];
    out[eb + be] = 1.f / (1.f + __expf(-logit_e * cf));
  }
}

extern "C" void kernel_launch(void* const* d_in, const int* in_sizes, int n_in,
                              void* d_out, int out_size, void* d_ws, size_t ws_size,
                              hipStream_t stream) {
  const float* h_i = (const float*)d_in[0];
  // d_in[1] (h_j) is unused by the reference
  const float* evol = (const float*)d_in[2];
  const float* evt = (const float*)d_in[3];
  const float* var_i = (const float*)d_in[4];
  const float* var_j = (const float*)d_in[5];
  const float* ct = (const float*)d_in[6];
  const float* Wq = (const float*)d_in[7];
  const float* bq = (const float*)d_in[8];
  const float* Wk = (const float*)d_in[9];
  const float* bk = (const float*)d_in[10];
  const float* Wv = (const float*)d_in[11];
  const float* bv = (const float*)d_in[12];
  const float* td = (const float*)d_in[13];
  const float* Wu = (const float*)d_in[14];
  const float* bu = (const float*)d_in[15];
  const float* Wo = (const float*)d_in[16];
  const float* bo = (const float*)d_in[17];
  float* out = (float*)d_out;

  char* ws = (char*)d_ws;
  unsigned short* Asw = (unsigned short*)ws;               // 512 KB
  unsigned short* Bvsw = (unsigned short*)(ws + 524288);   // 8 KB
  float* u_stack = (float*)(ws + 532480);                  // 4 KB
  unsigned short* gu = (unsigned short*)(ws + 536576);     // 4 KB
  float* consts = (float*)(ws + 540672);                   // 256 B
  float* r_g = (float*)(ws + 544768);                      // 1.6 MB
  unsigned short* Tsw = (unsigned short*)(ws + 2621440);   // 204.8 MB

  const int E = in_sizes[6];  // 100000 (divisible by 32)

  precomp_a<<<512, 256, 0, stream>>>(Wq, Wk, Asw);
  precomp_b<<<1, 256, 0, stream>>>(Wq, Wk, Wv, bq, bk, bv, Wo, bo, Wu,
                                   Bvsw, u_stack, gu, consts);
  proj_t<<<E / 32, 256, 0, stream>>>(h_i, Asw, Bvsw, u_stack, consts, Tsw, r_g);
  edge_epi<<<E / 16, 256, 0, stream>>>(evol, evt, var_i, var_j, ct, td, bu,
                                       Tsw, gu, r_g, consts, out);
}

// Round 5
// 671.029 us; speedup vs baseline: 1.1299x; 1.1299x over previous
//
#include <hip/hip_runtime.h>
#include <cstdint>
#include <cstddef>

#define DIM 256
#define NH 4
#define W 8
#define SCALE 0.125f

typedef __bf16 bf16x8 __attribute__((ext_vector_type(8)));
typedef float f32x4 __attribute__((ext_vector_type(4)));
typedef unsigned short u16x4 __attribute__((ext_vector_type(4)));

__device__ __forceinline__ f32x4 ld4(const float* p) { return *(const f32x4*)p; }
__device__ __forceinline__ f32x4 ld4_nt(const float* p) {
  return __builtin_nontemporal_load((const f32x4*)p);
}
__device__ __forceinline__ float b2f(unsigned short u) {
  unsigned int x = ((unsigned int)u) << 16;
  return __builtin_bit_cast(float, x);
}
__device__ __forceinline__ unsigned short f2b(float f) {
  __bf16 b = (__bf16)f;
  return __builtin_bit_cast(unsigned short, b);
}

// ---------------------------------------------------------------------------
// Precompute 1: Astack = [SCALE * Wq_n^T Wk_n]_n stacked to (256 k x 1024 col),
// bf16, MFMA-B-fragment layout: [kt 8][nt 64][lane 64][j 8],
// k = kt*32 + (lane>>4)*8 + j, col = nt*16 + (lane&15). LDS-staged operands.
// ---------------------------------------------------------------------------
__global__ void precomp_a(const float* __restrict__ Wq, const float* __restrict__ Wk,
                          unsigned short* __restrict__ Asw) {
  __shared__ float q_s[64][32];
  __shared__ float k_s[64][16];
  int blk = blockIdx.x;              // kt*64 + nt   (512 blocks)
  int kt = blk >> 6, nt = blk & 63;
  int n = nt >> 4;                   // head
  int tid = threadIdx.x;
  for (int i = tid; i < 2048; i += 256) {
    int d = i >> 5, k = i & 31;
    q_s[d][k] = Wq[(n * 64 + d) * 256 + kt * 32 + k];
  }
  for (int i = tid; i < 1024; i += 256) {
    int d = i >> 4, b = i & 15;
    k_s[d][b] = Wk[(n * 64 + d) * 256 + (nt & 15) * 16 + b];
  }
  __syncthreads();
  for (int x = tid; x < 512; x += 256) {
    int lane = x & 63, j = x >> 6;
    int kl = ((lane >> 4) * 8) + j;   // local k 0..31
    int c = lane & 15;                // local col 0..15
    float s = 0.f;
#pragma unroll 8
    for (int d = 0; d < 64; ++d) s += q_s[d][kl] * k_s[d][c];
    Asw[(size_t)blk * 512 + (size_t)lane * 8 + j] = f2b(s * SCALE);
  }
}

// ---------------------------------------------------------------------------
// Precompute 2: u_stack (f32), wvo (f32 [n][256]), Bvsw (bf16 swizzled
// bias-dot cols), consts s[4], c0. Biases are zero here but handled.
// ---------------------------------------------------------------------------
__global__ void precomp_b(const float* __restrict__ Wq, const float* __restrict__ Wk,
                          const float* __restrict__ Wv, const float* __restrict__ bq,
                          const float* __restrict__ bk, const float* __restrict__ bv,
                          const float* __restrict__ Wo, const float* __restrict__ bo,
                          unsigned short* __restrict__ Bvsw, float* __restrict__ u_stack,
                          float* __restrict__ wvo, float* __restrict__ consts) {
  __shared__ float v_s[1024];
  int t = threadIdx.x;
  for (int col = t; col < 1024; col += 256) {
    int n = col >> 8, b = col & 255;
    float su = 0.f, sw = 0.f, sv = 0.f;
#pragma unroll 8
    for (int d = 0; d < 64; ++d) {
      float wkv = Wk[(n * 64 + d) * 256 + b];
      su += bq[n * 64 + d] * wkv;
      sw += Wv[(n * 64 + d) * 256 + b] * Wo[n * 64 + d];
      sv += Wq[(n * 64 + d) * 256 + b] * bk[n * 64 + d];
    }
    u_stack[col] = su * SCALE;
    wvo[col] = sw;
    v_s[col] = sv * SCALE;
  }
  __syncthreads();
  for (int x = t; x < 8 * 64 * 8; x += 256) {   // Bvsw [kt][lane][j]
    int j = x & 7, lane = (x >> 3) & 63, kt = x >> 9;
    int colc = lane & 15;
    int k = kt * 32 + ((lane >> 4) * 8) + j;
    unsigned short val = 0;
    if (colc < 4) val = f2b(v_s[colc * 256 + k]);
    Bvsw[x] = val;
  }
  if (t < 4) {
    float s = 0.f;
    for (int d = 0; d < 64; ++d) s += bq[t * 64 + d] * bk[t * 64 + d];
    consts[t] = s * SCALE;
  }
  if (t == 4) {
    float s = bo[0];
    for (int d = 0; d < 256; ++d) s += bv[d] * Wo[d];
    consts[4] = s;
  }
}

// ---------------------------------------------------------------------------
// Kernel A: T = bf16(h) @ Astack.  M=32 per block (2 M-tiles share each
// B-fragment). Wave = head. T stored bf16 in edge_epi's per-lane layout:
// offset(edge, n, dim) = edge*1024 + n*256 + (dim>>5)*32 + ((dim>>2)&7)*4
//                        + (dim&3)        [i.e. [edge][n][k 8][c 8][j 4]]
// Also r_g[edge][4] = h . v_n + s_n (bias dots; zero-valued here).
// ---------------------------------------------------------------------------
__global__ __launch_bounds__(256, 2) void proj_t(
    const float* __restrict__ h_i, const unsigned short* __restrict__ Asw,
    const unsigned short* __restrict__ Bvsw, const float* __restrict__ u_stack,
    const float* __restrict__ consts,
    unsigned short* __restrict__ Tsw, float* __restrict__ r_g) {
  const int tid = threadIdx.x;
  const int wid = tid >> 6;        // head
  const int lane = tid & 63;
  const int e0 = blockIdx.x * 32;
  const int row = lane & 15, kg = lane >> 4;

  f32x4 zero4 = {0.f, 0.f, 0.f, 0.f};
  f32x4 acc0[16], acc1[16];
#pragma unroll
  for (int i = 0; i < 16; ++i) { acc0[i] = zero4; acc1[i] = zero4; }
  f32x4 accr0 = zero4, accr1 = zero4;

  const float* hrow0 = h_i + (size_t)(e0 + row) * DIM + kg * 8;
  const float* hrow1 = h_i + (size_t)(e0 + 16 + row) * DIM + kg * 8;
  const bf16x8* asw_b = (const bf16x8*)Asw;
  const bf16x8* bv_b = (const bf16x8*)Bvsw;

#pragma unroll
  for (int ks = 0; ks < 8; ++ks) {
    f32x4 a0 = ld4(hrow0 + ks * 32), a1 = ld4(hrow0 + ks * 32 + 4);
    f32x4 b0 = ld4(hrow1 + ks * 32), b1 = ld4(hrow1 + ks * 32 + 4);
    bf16x8 af0, af1;
#pragma unroll
    for (int j = 0; j < 4; ++j) {
      af0[j] = (__bf16)a0[j]; af0[j + 4] = (__bf16)a1[j];
      af1[j] = (__bf16)b0[j]; af1[j + 4] = (__bf16)b1[j];
    }
    const bf16x8* bb = asw_b + (size_t)(ks * 64 + wid * 16) * 64 + lane;
#pragma unroll
    for (int nt = 0; nt < 16; ++nt) {
      bf16x8 bf = bb[(size_t)nt * 64];
      acc0[nt] = __builtin_amdgcn_mfma_f32_16x16x32_bf16(af0, bf, acc0[nt], 0, 0, 0);
      acc1[nt] = __builtin_amdgcn_mfma_f32_16x16x32_bf16(af1, bf, acc1[nt], 0, 0, 0);
    }
    if (wid == 0) {
      bf16x8 bvf = bv_b[ks * 64 + lane];
      accr0 = __builtin_amdgcn_mfma_f32_16x16x32_bf16(af0, bvf, accr0, 0, 0, 0);
      accr1 = __builtin_amdgcn_mfma_f32_16x16x32_bf16(af1, bvf, accr1, 0, 0, 0);
    }
  }
  // D layout: edge = kg*4 + r, dim = nt*16 + row
#pragma unroll
  for (int nt = 0; nt < 16; ++nt) {
    float uv = u_stack[wid * 256 + nt * 16 + row];
    unsigned off = wid * 256 + (nt >> 1) * 32 + ((nt & 1) * 4 + (row >> 2)) * 4 + (row & 3);
#pragma unroll
    for (int r = 0; r < 4; ++r) {
      Tsw[(size_t)(e0 + kg * 4 + r) * 1024 + off] = f2b(acc0[nt][r] + uv);
      Tsw[(size_t)(e0 + 16 + kg * 4 + r) * 1024 + off] = f2b(acc1[nt][r] + uv);
    }
  }
  if (wid == 0 && row < 4) {
    float sv = consts[row];
#pragma unroll
    for (int r = 0; r < 4; ++r) {
      r_g[(size_t)(e0 + kg * 4 + r) * 4 + row] = accr0[r] + sv;
      r_g[(size_t)(e0 + 16 + kg * 4 + r) * 4 + row] = accr1[r] + sv;
    }
  }
}

// ---------------------------------------------------------------------------
// Kernel B: streaming epilogue. ONE WAVE PER EDGE, lane = (w=lane>>3, c=lane&7).
// All loads coalesced dwordx4 / dwordx2, issued up front, no LDS, no barriers,
// no MFMA. Reductions: dim-chunks via xor 1/2/4, softmax over w via 8/16/32.
// ---------------------------------------------------------------------------
__global__ __launch_bounds__(256, 5) void edge_epi(
    const float* __restrict__ evol, const float* __restrict__ evt,
    const float* __restrict__ var_i, const float* __restrict__ var_j,
    const float* __restrict__ cur_t, const float* __restrict__ tdp,
    const float* __restrict__ bup, const unsigned short* __restrict__ Tsw,
    const float* __restrict__ r_g, const float* __restrict__ wvo,
    const float* __restrict__ Wu, const float* __restrict__ consts,
    float* __restrict__ out) {

  const int tid = threadIdx.x;
  const int wid = tid >> 6;
  const int lane = tid & 63;
  const int e = blockIdx.x * 4 + wid;
  const int w = lane >> 3, c = lane & 7;

  // ---- issue the big HBM streams up front (independent dwordx4 bursts) ----
  const float* evb = evol + (size_t)e * (W * DIM) + w * DIM + c * 4;
  f32x4 ev[8];
#pragma unroll
  for (int k = 0; k < 8; ++k) ev[k] = ld4_nt(evb + k * 32);

  f32x4 vi = ld4_nt(var_i + (size_t)e * DIM + lane * 4);
  f32x4 vj = ld4_nt(var_j + (size_t)e * DIM + lane * 4);

  float tev = evt[(size_t)e * W + w];
  float ctv = cur_t[e];
  f32x4 rv4 = ld4(r_g + (size_t)e * 4);
  const float tdec = fabsf(tdp[0]);
  const float buv = bup[0];
  const float c0 = consts[4];

  // ---- dot products: dt[n], dg[n], du over this lane's 32 dims ----
  const unsigned short* tb = Tsw + (size_t)e * 1024 + c * 4;  // + n*256 + k*32
  const float* wvb = wvo + c * 4;
  const float* wub = Wu + c * 4;

  float dt[NH] = {0.f, 0.f, 0.f, 0.f};
  float dg[NH] = {0.f, 0.f, 0.f, 0.f};
  float du = 0.f;
#pragma unroll
  for (int n = 0; n < NH; ++n) {
#pragma unroll
    for (int k = 0; k < 8; ++k) {
      u16x4 t2 = *(const u16x4*)(tb + n * 256 + k * 32);   // 64B line, 8x dup->bcast
      f32x4 wv = ld4(wvb + n * 256 + k * 32);              // L1-hot
#pragma unroll
      for (int j = 0; j < 4; ++j) {
        dt[n] += ev[k][j] * b2f(t2[j]);
        dg[n] += ev[k][j] * wv[j];
      }
      if (n == 0) {
        f32x4 wu4 = ld4(wub + k * 32);                     // L1-hot
#pragma unroll
        for (int j = 0; j < 4; ++j) du += ev[k][j] * wu4[j];
      }
    }
  }

  // reduce over dim-chunks (8 lanes, strides 1/2/4)
#pragma unroll
  for (int s = 1; s < 8; s <<= 1) {
#pragma unroll
    for (int n = 0; n < NH; ++n) {
      dt[n] += __shfl_xor(dt[n], s);
      dg[n] += __shfl_xor(dg[n], s);
    }
    du += __shfl_xor(du, s);
  }

  // ---- per-window logits, softmax over w (strides 8/16/32) ----
  float tbias = -tdec * fmaxf(ctv - tev, 0.f);
  float unc = 1.f / (1.f + __expf(-(du + buv)));
  float L[NH], mx[NH];
#pragma unroll
  for (int n = 0; n < NH; ++n) {
    L[n] = (dt[n] + rv4[n] + tbias) * unc;
    mx[n] = L[n];
  }
#pragma unroll
  for (int s = 8; s < 64; s <<= 1)
#pragma unroll
    for (int n = 0; n < NH; ++n) mx[n] = fmaxf(mx[n], __shfl_xor(mx[n], s));
  float ps[NH], pg[NH];
#pragma unroll
  for (int n = 0; n < NH; ++n) {
    float p = __expf(L[n] - mx[n]);
    ps[n] = p;
    pg[n] = p * dg[n];
  }
#pragma unroll
  for (int s = 8; s < 64; s <<= 1)
#pragma unroll
    for (int n = 0; n < NH; ++n) {
      ps[n] += __shfl_xor(ps[n], s);
      pg[n] += __shfl_xor(pg[n], s);
    }
  float logit = pg[0] / ps[0] + pg[1] / ps[1] + pg[2] / ps[2] + pg[3] / ps[3] + c0;

  // ---- conf from var means (full-wave reduce) ----
  float si = vi[0] + vi[1] + vi[2] + vi[3];
  float sj = vj[0] + vj[1] + vj[2] + vj[3];
#pragma unroll
  for (int s = 1; s < 64; s <<= 1) {
    si += __shfl_xor(si, s);
    sj += __shfl_xor(sj, s);
  }
  if (lane == 0) {
    float ci = 1.f / (1.f + fmaxf(sqrtf(si * (1.f / 256.f)), 1e-6f));
    float cj = 1.f / (1.f + fmaxf(sqrtf(sj * (1.f / 256.f)), 1e-6f));
    out[e] = 1.f / (1.f + __expf(-logit * ci * cj));
  }
}

extern "C" void kernel_launch(void* const* d_in, const int* in_sizes, int n_in,
                              void* d_out, int out_size, void* d_ws, size_t ws_size,
                              hipStream_t stream) {
  const float* h_i = (const float*)d_in[0];
  // d_in[1] (h_j) is unused by the reference
  const float* evol = (const float*)d_in[2];
  const float* evt = (const float*)d_in[3];
  const float* var_i = (const float*)d_in[4];
  const float* var_j = (const float*)d_in[5];
  const float* ct = (const float*)d_in[6];
  const float* Wq = (const float*)d_in[7];
  const float* bq = (const float*)d_in[8];
  const float* Wk = (const float*)d_in[9];
  const float* bk = (const float*)d_in[10];
  const float* Wv = (const float*)d_in[11];
  const float* bv = (const float*)d_in[12];
  const float* td = (const float*)d_in[13];
  const float* Wu = (const float*)d_in[14];
  const float* bu = (const float*)d_in[15];
  const float* Wo = (const float*)d_in[16];
  const float* bo = (const float*)d_in[17];
  float* out = (float*)d_out;

  char* ws = (char*)d_ws;
  unsigned short* Asw = (unsigned short*)ws;               // 512 KB
  unsigned short* Bvsw = (unsigned short*)(ws + 524288);   // 8 KB
  float* u_stack = (float*)(ws + 532480);                  // 4 KB
  float* wvo = (float*)(ws + 536576);                      // 4 KB
  float* consts = (float*)(ws + 540672);                   // 256 B
  float* r_g = (float*)(ws + 544768);                      // 1.6 MB
  unsigned short* Tsw = (unsigned short*)(ws + 2621440);   // 204.8 MB

  const int E = in_sizes[6];  // 100000 (divisible by 32 and 4)

  precomp_a<<<512, 256, 0, stream>>>(Wq, Wk, Asw);
  precomp_b<<<1, 256, 0, stream>>>(Wq, Wk, Wv, bq, bk, bv, Wo, bo,
                                   Bvsw, u_stack, wvo, consts);
  proj_t<<<E / 32, 256, 0, stream>>>(h_i, Asw, Bvsw, u_stack, consts, Tsw, r_g);
  edge_epi<<<E / 4, 256, 0, stream>>>(evol, evt, var_i, var_j, ct, td, bu,
                                      Tsw, r_g, wvo, Wu, consts, out);
}

// Round 6
// 512.785 us; speedup vs baseline: 1.4786x; 1.3086x over previous
//
#include <hip/hip_runtime.h>
#include <cstdint>
#include <cstddef>

#define DIM 256
#define NH 4
#define W 8
#define EB 16
#define SCALE 0.125f

typedef __bf16 bf16x8 __attribute__((ext_vector_type(8)));
typedef float f32x4 __attribute__((ext_vector_type(4)));
typedef unsigned short u16x4 __attribute__((ext_vector_type(4)));

__device__ __forceinline__ f32x4 ld4(const float* p) { return *(const f32x4*)p; }
__device__ __forceinline__ f32x4 ld4_nt(const float* p) {
  return __builtin_nontemporal_load((const f32x4*)p);
}
__device__ __forceinline__ float b2f(unsigned short u) {
  unsigned int x = ((unsigned int)u) << 16;
  return __builtin_bit_cast(float, x);
}
__device__ __forceinline__ unsigned short f2b(float f) {
  __bf16 b = (__bf16)f;
  return __builtin_bit_cast(unsigned short, b);
}

// ---------------------------------------------------------------------------
// Precompute 1: Astack = [SCALE * Wq_n^T Wk_n]_n stacked to (256 k x 1024 col),
// bf16, MFMA-B-fragment layout: [kt 8][nt 64][lane 64][j 8],
// k = kt*32 + (lane>>4)*8 + j, col = nt*16 + (lane&15). LDS-staged operands.
// ---------------------------------------------------------------------------
__global__ void precomp_a(const float* __restrict__ Wq, const float* __restrict__ Wk,
                          unsigned short* __restrict__ Asw) {
  __shared__ float q_s[64][32];
  __shared__ float k_s[64][16];
  int blk = blockIdx.x;              // kt*64 + nt   (512 blocks)
  int kt = blk >> 6, nt = blk & 63;
  int n = nt >> 4;                   // head
  int tid = threadIdx.x;
  for (int i = tid; i < 2048; i += 256) {
    int d = i >> 5, k = i & 31;
    q_s[d][k] = Wq[(n * 64 + d) * 256 + kt * 32 + k];
  }
  for (int i = tid; i < 1024; i += 256) {
    int d = i >> 4, b = i & 15;
    k_s[d][b] = Wk[(n * 64 + d) * 256 + (nt & 15) * 16 + b];
  }
  __syncthreads();
  for (int x = tid; x < 512; x += 256) {
    int lane = x & 63, j = x >> 6;
    int kl = ((lane >> 4) * 8) + j;   // local k 0..31
    int c = lane & 15;                // local col 0..15
    float s = 0.f;
#pragma unroll 8
    for (int d = 0; d < 64; ++d) s += q_s[d][kl] * k_s[d][c];
    Asw[(size_t)blk * 512 + (size_t)lane * 8 + j] = f2b(s * SCALE);
  }
}

// ---------------------------------------------------------------------------
// Precompute 2 (general-bias terms; zero-valued here but handled): u_stack,
// wvo (f32), Bvsw (bf16 swizzled bias-dot cols), consts s[4], c0.
// ---------------------------------------------------------------------------
__global__ void precomp_b(const float* __restrict__ Wq, const float* __restrict__ Wk,
                          const float* __restrict__ Wv, const float* __restrict__ bq,
                          const float* __restrict__ bk, const float* __restrict__ bv,
                          const float* __restrict__ Wo, const float* __restrict__ bo,
                          unsigned short* __restrict__ Bvsw, float* __restrict__ u_stack,
                          float* __restrict__ wvo, float* __restrict__ consts) {
  __shared__ float v_s[1024];
  int t = threadIdx.x;
  for (int col = t; col < 1024; col += 256) {
    int n = col >> 8, b = col & 255;
    float su = 0.f, sw = 0.f, sv = 0.f;
#pragma unroll 8
    for (int d = 0; d < 64; ++d) {
      float wkv = Wk[(n * 64 + d) * 256 + b];
      su += bq[n * 64 + d] * wkv;
      sw += Wv[(n * 64 + d) * 256 + b] * Wo[n * 64 + d];
      sv += Wq[(n * 64 + d) * 256 + b] * bk[n * 64 + d];
    }
    u_stack[col] = su * SCALE;
    wvo[col] = sw;
    v_s[col] = sv * SCALE;
  }
  __syncthreads();
  for (int x = t; x < 8 * 64 * 8; x += 256) {   // Bvsw [kt][lane][j]
    int j = x & 7, lane = (x >> 3) & 63, kt = x >> 9;
    int colc = lane & 15;
    int k = kt * 32 + ((lane >> 4) * 8) + j;
    unsigned short val = 0;
    if (colc < 4) val = f2b(v_s[colc * 256 + k]);
    Bvsw[x] = val;
  }
  if (t < 4) {
    float s = 0.f;
    for (int d = 0; d < 64; ++d) s += bq[t * 64 + d] * bk[t * 64 + d];
    consts[t] = s * SCALE;
  }
  if (t == 4) {
    float s = bo[0];
    for (int d = 0; d < 256; ++d) s += bv[d] * Wo[d];
    consts[4] = s;
  }
}

// ---------------------------------------------------------------------------
// Fused main kernel (R1 structure + raw-barrier pipelined staging):
//  phase 1: t = bf16(h) @ Astack via MFMA (wave n owns head n) -> t_lds (bf16)
//  phase 2: 16 one-edge chunks; ev_lds[2] ping-pong; global loads issued TWO
//           chunks ahead into regs; ds_write of chunk m+1 before compute of
//           chunk m; ONE raw s_barrier per chunk with lgkmcnt(0) only — the
//           HBM queue is never drained (no vmcnt(0) in the loop).
//  phase 3: var means, combine heads, sigmoid -> out
// ---------------------------------------------------------------------------
__global__ __launch_bounds__(256, 3) void fused_main(
    const float* __restrict__ h_i, const float* __restrict__ evol,
    const float* __restrict__ evt, const float* __restrict__ var_i,
    const float* __restrict__ var_j, const float* __restrict__ cur_t,
    const float* __restrict__ tdp, const float* __restrict__ Wu,
    const float* __restrict__ bup, const unsigned short* __restrict__ Asw,
    const unsigned short* __restrict__ Bvsw, const float* __restrict__ u_stack,
    const float* __restrict__ wvo, const float* __restrict__ consts,
    float* __restrict__ out) {

  __shared__ unsigned short t_lds[EB * 1024];   // 32 KB  (bf16 bits)
  __shared__ float ev_lds[2][2048];             // 16 KB  (1-edge dbuf)
  __shared__ float part_lds[EB][NH];            // 256 B
  __shared__ float r_lds[EB][NH];               // 256 B

  const int tid = threadIdx.x;
  const int wid = tid >> 6;        // wave index == head index
  const int lane = tid & 63;
  const int e0 = blockIdx.x * EB;

  // ---------------- phase 1: GEMM t = h @ Astack ----------------
  const int row = lane & 15;       // edge within block (M)
  const int kg = lane >> 4;        // k-group
  f32x4 zero4 = {0.f, 0.f, 0.f, 0.f};
  f32x4 acc[16];
#pragma unroll
  for (int i = 0; i < 16; ++i) acc[i] = zero4;
  f32x4 accr = zero4;

  const float* hrow = h_i + (size_t)(e0 + row) * DIM + kg * 8;
  const bf16x8* asw_b = (const bf16x8*)Asw;
  const bf16x8* bv_b = (const bf16x8*)Bvsw;

#pragma unroll
  for (int ks = 0; ks < 8; ++ks) {
    f32x4 a0 = ld4(hrow + ks * 32);
    f32x4 a1 = ld4(hrow + ks * 32 + 4);
    bf16x8 af;
    af[0] = (__bf16)a0[0]; af[1] = (__bf16)a0[1]; af[2] = (__bf16)a0[2]; af[3] = (__bf16)a0[3];
    af[4] = (__bf16)a1[0]; af[5] = (__bf16)a1[1]; af[6] = (__bf16)a1[2]; af[7] = (__bf16)a1[3];
    const bf16x8* bb = asw_b + (size_t)(ks * 64 + wid * 16) * 64 + lane;
#pragma unroll
    for (int nt = 0; nt < 16; ++nt) {
      bf16x8 bf = bb[(size_t)nt * 64];
      acc[nt] = __builtin_amdgcn_mfma_f32_16x16x32_bf16(af, bf, acc[nt], 0, 0, 0);
    }
    if (wid == 0) {  // extra tile: r[edge][n] = h . v_n  (bias term; zero here)
      bf16x8 bvf = bv_b[ks * 64 + lane];
      accr = __builtin_amdgcn_mfma_f32_16x16x32_bf16(af, bvf, accr, 0, 0, 0);
    }
  }
  // D layout: edge = kg*4 + r, dim = wid*256 + nt*16 + row   [m89-verified]
#pragma unroll
  for (int nt = 0; nt < 16; ++nt) {
    int dim = wid * 256 + nt * 16 + row;
    float uv = u_stack[dim];
#pragma unroll
    for (int r = 0; r < 4; ++r)
      t_lds[(kg * 4 + r) * 1024 + dim] = f2b(acc[nt][r] + uv);
  }
  if (wid == 0 && row < 4) {
    float sv = consts[row];
#pragma unroll
    for (int r = 0; r < 4; ++r) r_lds[kg * 4 + r][row] = accr[r] + sv;
  }

  // epilogue constants/operands (L2-hot)
  const int c = lane & 7;          // dim-chunk index (dims c*4 + 32k + j)
  const int oct = lane >> 3;       // window index
  f32x4 wvoR[8], wuR[8];
#pragma unroll
  for (int k = 0; k < 8; ++k) {
    wvoR[k] = ld4(wvo + wid * 256 + k * 32 + c * 4);
    wuR[k] = ld4(Wu + k * 32 + c * 4);
  }
  const float tdec = fabsf(tdp[0]);
  const float buv = bup[0];

  // ---------------- staging prologue ----------------
  // chunk = one edge = 2048 floats; thread covers floats [tid*4, +4) and
  // [1024 + tid*4, +4)  (contiguous block-wide, b128 per lane).
  const float* evg = evol + (size_t)e0 * (W * DIM);
  f32x4 rA[2], rB[2];
  rA[0] = ld4_nt(evg + tid * 4);
  rB[0] = ld4_nt(evg + 1024 + tid * 4);
  rA[1] = ld4_nt(evg + 2048 + tid * 4);
  rB[1] = ld4_nt(evg + 2048 + 1024 + tid * 4);
  *(f32x4*)&ev_lds[0][tid * 4] = rA[0];
  *(f32x4*)&ev_lds[0][1024 + tid * 4] = rB[0];
  asm volatile("s_waitcnt lgkmcnt(0)" ::: "memory");
  __builtin_amdgcn_s_barrier();      // buf0 ready; r_lds/t_lds visible
  __builtin_amdgcn_sched_barrier(0);

  // ---------------- phase 2: pipelined chunk loop ----------------
#pragma unroll
  for (int m = 0; m < EB; ++m) {
    const int sl = m & 1, sn = (m + 1) & 1;
    if (m + 2 < EB) {                 // issue chunk m+2 (slot sl just freed)
      rA[sl] = ld4_nt(evg + (size_t)(m + 2) * 2048 + tid * 4);
      rB[sl] = ld4_nt(evg + (size_t)(m + 2) * 2048 + 1024 + tid * 4);
    }
    if (m + 1 < EB) {                 // write chunk m+1 (counted vmcnt wait)
      *(f32x4*)&ev_lds[sn][tid * 4] = rA[sn];
      *(f32x4*)&ev_lds[sn][1024 + tid * 4] = rB[sn];
    }
    // ---- compute edge m from ev_lds[sl] ----
    {
      const float* evb = &ev_lds[sl][oct * 256 + c * 4];
      const unsigned short* tb = &t_lds[m * 1024 + wid * 256 + c * 4];
      float dt = 0.f, dg = 0.f, du = 0.f;
#pragma unroll
      for (int k = 0; k < 8; ++k) {
        f32x4 evv = ld4(evb + k * 32);
        u16x4 tu = *(const u16x4*)(tb + k * 32);
        dt += evv[0] * b2f(tu[0]) + evv[1] * b2f(tu[1]) + evv[2] * b2f(tu[2]) + evv[3] * b2f(tu[3]);
        dg += evv[0] * wvoR[k][0] + evv[1] * wvoR[k][1] + evv[2] * wvoR[k][2] + evv[3] * wvoR[k][3];
        du += evv[0] * wuR[k][0] + evv[1] * wuR[k][1] + evv[2] * wuR[k][2] + evv[3] * wuR[k][3];
      }
#pragma unroll
      for (int s = 1; s < 8; s <<= 1) {   // reduce over dim-chunks in octet
        dt += __shfl_xor(dt, s);
        dg += __shfl_xor(dg, s);
        du += __shfl_xor(du, s);
      }
      float tev = evt[(size_t)(e0 + m) * W + oct];
      float tbias = -tdec * fmaxf(cur_t[e0 + m] - tev, 0.f);
      float unc = 1.f / (1.f + __expf(-(du + buv)));
      float logit = (dt + r_lds[m][wid] + tbias) * unc;
      float mx = logit;
#pragma unroll
      for (int s = 8; s < 64; s <<= 1) mx = fmaxf(mx, __shfl_xor(mx, s));
      float p = __expf(logit - mx);
      float pg = p * dg, ps = p;
#pragma unroll
      for (int s = 8; s < 64; s <<= 1) { ps += __shfl_xor(ps, s); pg += __shfl_xor(pg, s); }
      if (lane == 0) part_lds[m][wid] = pg / ps;   // head's pooled . Wo_n
    }
    asm volatile("s_waitcnt lgkmcnt(0)" ::: "memory");
    __builtin_amdgcn_s_barrier();     // chunk m consumed; chunk m+1 ready
    __builtin_amdgcn_sched_barrier(0);
  }

  // ---------------- phase 3: conf + output ----------------
  const float c0 = consts[4];
#pragma unroll
  for (int e = 0; e < 4; ++e) {
    const int m = wid * 4 + e;
    f32x4 vi = ld4_nt(var_i + (size_t)(e0 + m) * DIM + lane * 4);
    f32x4 vj = ld4_nt(var_j + (size_t)(e0 + m) * DIM + lane * 4);
    float si = vi[0] + vi[1] + vi[2] + vi[3];
    float sj = vj[0] + vj[1] + vj[2] + vj[3];
#pragma unroll
    for (int s = 1; s < 64; s <<= 1) { si += __shfl_xor(si, s); sj += __shfl_xor(sj, s); }
    if (lane == 0) {
      float logit = part_lds[m][0] + part_lds[m][1] + part_lds[m][2] + part_lds[m][3] + c0;
      float ci = 1.f / (1.f + fmaxf(sqrtf(si * (1.f / 256.f)), 1e-6f));
      float cj = 1.f / (1.f + fmaxf(sqrtf(sj * (1.f / 256.f)), 1e-6f));
      out[e0 + m] = 1.f / (1.f + __expf(-logit * ci * cj));
    }
  }
}

extern "C" void kernel_launch(void* const* d_in, const int* in_sizes, int n_in,
                              void* d_out, int out_size, void* d_ws, size_t ws_size,
                              hipStream_t stream) {
  const float* h_i = (const float*)d_in[0];
  // d_in[1] (h_j) is unused by the reference
  const float* evol = (const float*)d_in[2];
  const float* evt = (const float*)d_in[3];
  const float* var_i = (const float*)d_in[4];
  const float* var_j = (const float*)d_in[5];
  const float* ct = (const float*)d_in[6];
  const float* Wq = (const float*)d_in[7];
  const float* bq = (const float*)d_in[8];
  const float* Wk = (const float*)d_in[9];
  const float* bk = (const float*)d_in[10];
  const float* Wv = (const float*)d_in[11];
  const float* bv = (const float*)d_in[12];
  const float* td = (const float*)d_in[13];
  const float* Wu = (const float*)d_in[14];
  const float* bu = (const float*)d_in[15];
  const float* Wo = (const float*)d_in[16];
  const float* bo = (const float*)d_in[17];
  float* out = (float*)d_out;

  char* ws = (char*)d_ws;
  unsigned short* Asw = (unsigned short*)ws;               // 512 KB
  unsigned short* Bvsw = (unsigned short*)(ws + 524288);   // 8 KB
  float* u_stack = (float*)(ws + 532480);                  // 4 KB
  float* wvo = (float*)(ws + 536576);                      // 4 KB
  float* consts = (float*)(ws + 540672);                   // 32 B

  const int E = in_sizes[6];  // 100000; EB=16 divides exactly (6250 blocks)

  precomp_a<<<512, 256, 0, stream>>>(Wq, Wk, Asw);
  precomp_b<<<1, 256, 0, stream>>>(Wq, Wk, Wv, bq, bk, bv, Wo, bo,
                                   Bvsw, u_stack, wvo, consts);
  fused_main<<<E / EB, 256, 0, stream>>>(h_i, evol, evt, var_i, var_j, ct, td, Wu, bu,
                                         Asw, Bvsw, u_stack, wvo, consts, out);
}

// Round 7
// 347.973 us; speedup vs baseline: 2.1789x; 1.4736x over previous
//
#include <hip/hip_runtime.h>
#include <cstdint>
#include <cstddef>

#define DIM 256
#define NH 4
#define W 8
#define EB 16
#define SCALE 0.125f

typedef __bf16 bf16x8 __attribute__((ext_vector_type(8)));
typedef float f32x4 __attribute__((ext_vector_type(4)));
typedef unsigned short u16x4 __attribute__((ext_vector_type(4)));

__device__ __forceinline__ f32x4 ld4(const float* p) { return *(const f32x4*)p; }
__device__ __forceinline__ f32x4 ld4_nt(const float* p) {
  return __builtin_nontemporal_load((const f32x4*)p);
}
__device__ __forceinline__ float b2f(unsigned short u) {
  unsigned int x = ((unsigned int)u) << 16;
  return __builtin_bit_cast(float, x);
}
__device__ __forceinline__ unsigned short f2b(float f) {
  __bf16 b = (__bf16)f;
  return __builtin_bit_cast(unsigned short, b);
}

// ---------------------------------------------------------------------------
// Pack Wq (x SCALE) and Wk into MFMA-B-fragment bf16 layouts (pure permute):
//  Bqsw [kt 8][nt 16][lane 64][j 8]: B[k][qcol], k=kt*32+(lane>>4)*8+j,
//       qcol=nt*16+(lane&15), val=SCALE*Wq[qcol][k]
//  Bksw [n 4][kt 2][nt 16][lane 64][j 8]: per-head B2[kk][b], kk=kt*32+...,
//       b=nt*16+(lane&15), val=Wk[n*64+kk][b]
// ---------------------------------------------------------------------------
__global__ void precomp_pack(const float* __restrict__ Wq, const float* __restrict__ Wk,
                             unsigned short* __restrict__ Bqsw,
                             unsigned short* __restrict__ Bksw) {
  int i = blockIdx.x * 256 + threadIdx.x;   // 0..65535
  int j = i & 7, lane = (i >> 3) & 63, nt = (i >> 9) & 15;
  int col15 = lane & 15, kg = lane >> 4;
  int kt = i >> 13;                          // 0..7
  Bqsw[i] = f2b(SCALE * Wq[(nt * 16 + col15) * 256 + kt * 32 + kg * 8 + j]);
  int kt2 = (i >> 13) & 1, n = i >> 14;
  Bksw[i] = f2b(Wk[(n * 64 + kt2 * 32 + kg * 8 + j) * 256 + nt * 16 + col15]);
}

// ---------------------------------------------------------------------------
// wvo[n][256] = Wv_n^T Wo_n (f32), consts[0] = bo + bv.Wo
// ---------------------------------------------------------------------------
__global__ void precomp_b(const float* __restrict__ Wv, const float* __restrict__ bv,
                          const float* __restrict__ Wo, const float* __restrict__ bo,
                          float* __restrict__ wvo, float* __restrict__ consts) {
  int t = threadIdx.x;
  for (int col = t; col < 1024; col += 256) {
    int n = col >> 8, b = col & 255;
    float sw = 0.f;
#pragma unroll 8
    for (int d = 0; d < 64; ++d)
      sw += Wv[(n * 64 + d) * 256 + b] * Wo[n * 64 + d];
    wvo[col] = sw;
  }
  if (t == 0) {
    float s = bo[0];
    for (int d = 0; d < 256; ++d) s += bv[d] * Wo[d];
    consts[0] = s;
  }
}

// ---------------------------------------------------------------------------
// Fused main kernel. Phase 1 uses the rank-64 factorization:
//   GEMM1: q = SCALE*(h@Wq^T + bq)  (wave n owns q-cols [64n,64n+64))
//   q -> small LDS bounce (overlaid on ev_lds, intra-wave) -> A-frags
//   r_n = q_n . bk_n  (in-register dot, absorbs all bias terms)
//   GEMM2: t_n = q_n @ Wk_n rows    (K=64, N=256) -> t_lds (bf16)
// Phase 2: R6's raw-barrier pipelined ev staging + per-head dots + softmax.
// Phase 3: var means, combine heads, sigmoid.
// ---------------------------------------------------------------------------
__global__ __launch_bounds__(256, 3) void fused_main(
    const float* __restrict__ h_i, const float* __restrict__ evol,
    const float* __restrict__ evt, const float* __restrict__ var_i,
    const float* __restrict__ var_j, const float* __restrict__ cur_t,
    const float* __restrict__ tdp, const float* __restrict__ Wu,
    const float* __restrict__ bup, const float* __restrict__ bq,
    const float* __restrict__ bk, const unsigned short* __restrict__ Bqsw,
    const unsigned short* __restrict__ Bksw, const float* __restrict__ wvo,
    const float* __restrict__ consts, float* __restrict__ out) {

  __shared__ unsigned short t_lds[EB * 1024];   // 32 KB  (bf16 bits)
  __shared__ float ev_lds[2][2048];             // 16 KB  (1-edge dbuf; q overlay)
  __shared__ float part_lds[EB][NH];            // 256 B
  __shared__ float r_lds[EB][NH];               // 256 B

  const int tid = threadIdx.x;
  const int wid = tid >> 6;        // wave index == head index
  const int lane = tid & 63;
  const int e0 = blockIdx.x * EB;

  const int col15 = lane & 15;     // D-col / A-row index
  const int kg = lane >> 4;        // k-group

  // ---------------- phase 1a: GEMM1 q = SCALE*(h @ Wq^T + bq) ----------------
  f32x4 zero4 = {0.f, 0.f, 0.f, 0.f};
  f32x4 qacc[4];
#pragma unroll
  for (int i = 0; i < 4; ++i) qacc[i] = zero4;

  const float* hrow = h_i + (size_t)(e0 + col15) * DIM + kg * 8;
  const bf16x8* bq_b = (const bf16x8*)Bqsw;

#pragma unroll
  for (int ks = 0; ks < 8; ++ks) {
    f32x4 a0 = ld4(hrow + ks * 32);
    f32x4 a1 = ld4(hrow + ks * 32 + 4);
    bf16x8 af;
#pragma unroll
    for (int j = 0; j < 4; ++j) { af[j] = (__bf16)a0[j]; af[j + 4] = (__bf16)a1[j]; }
    const bf16x8* bb = bq_b + (size_t)(ks * 16 + wid * 4) * 64 + lane;
#pragma unroll
    for (int ntl = 0; ntl < 4; ++ntl)
      qacc[ntl] = __builtin_amdgcn_mfma_f32_16x16x32_bf16(af, bb[(size_t)ntl * 64], qacc[ntl], 0, 0, 0);
  }

  // q -> LDS bounce (row stride 144 B = conflict-free), + SCALE*bq
  char* qregion = (char*)ev_lds + wid * 2304;
#pragma unroll
  for (int ntl = 0; ntl < 4; ++ntl) {
    float bqv = SCALE * bq[wid * 64 + ntl * 16 + col15];
#pragma unroll
    for (int r = 0; r < 4; ++r)
      *(unsigned short*)(qregion + (kg * 4 + r) * 144 + (ntl * 16 + col15) * 2) =
          f2b(qacc[ntl][r] + bqv);
  }
  asm volatile("s_waitcnt lgkmcnt(0)" ::: "memory");

  // A-frags for GEMM2: qa[kt] = q[edge=col15][kt*32 + kg*8 .. +8]
  bf16x8 qa[2];
  qa[0] = *(const bf16x8*)(qregion + col15 * 144 + kg * 16);
  qa[1] = *(const bf16x8*)(qregion + col15 * 144 + 64 + kg * 16);

  // r[edge][n] = q_n . bk_n   (zero-valued here; handled generally)
  {
    float rp = 0.f;
#pragma unroll
    for (int kt = 0; kt < 2; ++kt) {
      f32x4 b0 = ld4(bk + wid * 64 + kt * 32 + kg * 8);
      f32x4 b1 = ld4(bk + wid * 64 + kt * 32 + kg * 8 + 4);
#pragma unroll
      for (int j = 0; j < 4; ++j)
        rp += (float)qa[kt][j] * b0[j] + (float)qa[kt][j + 4] * b1[j];
    }
    rp += __shfl_xor(rp, 16);
    rp += __shfl_xor(rp, 32);
    if (lane < 16) r_lds[lane][wid] = rp;
  }

  // ---------------- phase 1b: GEMM2 t_n = q_n @ Wk_n ----------------
  f32x4 tacc[16];
#pragma unroll
  for (int i = 0; i < 16; ++i) tacc[i] = zero4;
  const bf16x8* bk_b = (const bf16x8*)Bksw;
#pragma unroll
  for (int kt = 0; kt < 2; ++kt) {
    const bf16x8* bb = bk_b + (size_t)((wid * 2 + kt) * 16) * 64 + lane;
#pragma unroll
    for (int nt = 0; nt < 16; ++nt)
      tacc[nt] = __builtin_amdgcn_mfma_f32_16x16x32_bf16(qa[kt], bb[(size_t)nt * 64], tacc[nt], 0, 0, 0);
  }
  // D: edge = kg*4 + r, dim = wid*256 + nt*16 + col15  (intra-wave for phase 2)
#pragma unroll
  for (int nt = 0; nt < 16; ++nt) {
    int dim = wid * 256 + nt * 16 + col15;
#pragma unroll
    for (int r = 0; r < 4; ++r)
      t_lds[(kg * 4 + r) * 1024 + dim] = f2b(tacc[nt][r]);
  }

  // epilogue constants/operands (L2-hot)
  const int c = lane & 7;          // dim-chunk index
  const int oct = lane >> 3;       // window index
  f32x4 wvoR[8], wuR[8];
#pragma unroll
  for (int k = 0; k < 8; ++k) {
    wvoR[k] = ld4(wvo + wid * 256 + k * 32 + c * 4);
    wuR[k] = ld4(Wu + k * 32 + c * 4);
  }
  const float tdec = fabsf(tdp[0]);
  const float buv = bup[0];

  // ---------------- staging prologue (q region dead after barrier) ----------
  const float* evg = evol + (size_t)e0 * (W * DIM);
  f32x4 rA[2], rB[2];
  rA[0] = ld4_nt(evg + tid * 4);
  rB[0] = ld4_nt(evg + 1024 + tid * 4);
  rA[1] = ld4_nt(evg + 2048 + tid * 4);
  rB[1] = ld4_nt(evg + 2048 + 1024 + tid * 4);
  __builtin_amdgcn_s_barrier();      // all waves done reading q overlay
  __builtin_amdgcn_sched_barrier(0);
  *(f32x4*)&ev_lds[0][tid * 4] = rA[0];
  *(f32x4*)&ev_lds[0][1024 + tid * 4] = rB[0];
  asm volatile("s_waitcnt lgkmcnt(0)" ::: "memory");
  __builtin_amdgcn_s_barrier();      // buf0 ready
  __builtin_amdgcn_sched_barrier(0);

  // ---------------- phase 2: pipelined chunk loop (R6) ----------------
#pragma unroll
  for (int m = 0; m < EB; ++m) {
    const int sl = m & 1, sn = (m + 1) & 1;
    if (m + 2 < EB) {                 // issue chunk m+2
      rA[sl] = ld4_nt(evg + (size_t)(m + 2) * 2048 + tid * 4);
      rB[sl] = ld4_nt(evg + (size_t)(m + 2) * 2048 + 1024 + tid * 4);
    }
    if (m + 1 < EB) {                 // write chunk m+1 (counted vmcnt wait)
      *(f32x4*)&ev_lds[sn][tid * 4] = rA[sn];
      *(f32x4*)&ev_lds[sn][1024 + tid * 4] = rB[sn];
    }
    {
      const float* evb = &ev_lds[sl][oct * 256 + c * 4];
      const unsigned short* tb = &t_lds[m * 1024 + wid * 256 + c * 4];
      float dt = 0.f, dg = 0.f, du = 0.f;
#pragma unroll
      for (int k = 0; k < 8; ++k) {
        f32x4 evv = ld4(evb + k * 32);
        u16x4 tu = *(const u16x4*)(tb + k * 32);
        dt += evv[0] * b2f(tu[0]) + evv[1] * b2f(tu[1]) + evv[2] * b2f(tu[2]) + evv[3] * b2f(tu[3]);
        dg += evv[0] * wvoR[k][0] + evv[1] * wvoR[k][1] + evv[2] * wvoR[k][2] + evv[3] * wvoR[k][3];
        du += evv[0] * wuR[k][0] + evv[1] * wuR[k][1] + evv[2] * wuR[k][2] + evv[3] * wuR[k][3];
      }
#pragma unroll
      for (int s = 1; s < 8; s <<= 1) {
        dt += __shfl_xor(dt, s);
        dg += __shfl_xor(dg, s);
        du += __shfl_xor(du, s);
      }
      float tev = evt[(size_t)(e0 + m) * W + oct];
      float tbias = -tdec * fmaxf(cur_t[e0 + m] - tev, 0.f);
      float unc = 1.f / (1.f + __expf(-(du + buv)));
      float logit = (dt + r_lds[m][wid] + tbias) * unc;
      float mx = logit;
#pragma unroll
      for (int s = 8; s < 64; s <<= 1) mx = fmaxf(mx, __shfl_xor(mx, s));
      float p = __expf(logit - mx);
      float pg = p * dg, ps = p;
#pragma unroll
      for (int s = 8; s < 64; s <<= 1) { ps += __shfl_xor(ps, s); pg += __shfl_xor(pg, s); }
      if (lane == 0) part_lds[m][wid] = pg / ps;
    }
    asm volatile("s_waitcnt lgkmcnt(0)" ::: "memory");
    __builtin_amdgcn_s_barrier();     // chunk m consumed; chunk m+1 ready
    __builtin_amdgcn_sched_barrier(0);
  }

  // ---------------- phase 3: conf + output ----------------
  const float c0 = consts[0];
#pragma unroll
  for (int e = 0; e < 4; ++e) {
    const int m = wid * 4 + e;
    f32x4 vi = ld4_nt(var_i + (size_t)(e0 + m) * DIM + lane * 4);
    f32x4 vj = ld4_nt(var_j + (size_t)(e0 + m) * DIM + lane * 4);
    float si = vi[0] + vi[1] + vi[2] + vi[3];
    float sj = vj[0] + vj[1] + vj[2] + vj[3];
#pragma unroll
    for (int s = 1; s < 64; s <<= 1) { si += __shfl_xor(si, s); sj += __shfl_xor(sj, s); }
    if (lane == 0) {
      float logit = part_lds[m][0] + part_lds[m][1] + part_lds[m][2] + part_lds[m][3] + c0;
      float ci = 1.f / (1.f + fmaxf(sqrtf(si * (1.f / 256.f)), 1e-6f));
      float cj = 1.f / (1.f + fmaxf(sqrtf(sj * (1.f / 256.f)), 1e-6f));
      out[e0 + m] = 1.f / (1.f + __expf(-logit * ci * cj));
    }
  }
}

extern "C" void kernel_launch(void* const* d_in, const int* in_sizes, int n_in,
                              void* d_out, int out_size, void* d_ws, size_t ws_size,
                              hipStream_t stream) {
  const float* h_i = (const float*)d_in[0];
  // d_in[1] (h_j) is unused by the reference
  const float* evol = (const float*)d_in[2];
  const float* evt = (const float*)d_in[3];
  const float* var_i = (const float*)d_in[4];
  const float* var_j = (const float*)d_in[5];
  const float* ct = (const float*)d_in[6];
  const float* Wq = (const float*)d_in[7];
  const float* bq = (const float*)d_in[8];
  const float* Wk = (const float*)d_in[9];
  const float* bk = (const float*)d_in[10];
  const float* Wv = (const float*)d_in[11];
  const float* bv = (const float*)d_in[12];
  const float* td = (const float*)d_in[13];
  const float* Wu = (const float*)d_in[14];
  const float* bu = (const float*)d_in[15];
  const float* Wo = (const float*)d_in[16];
  const float* bo = (const float*)d_in[17];
  float* out = (float*)d_out;

  char* ws = (char*)d_ws;
  unsigned short* Bqsw = (unsigned short*)ws;               // 128 KB
  unsigned short* Bksw = (unsigned short*)(ws + 131072);    // 128 KB
  float* wvo = (float*)(ws + 262144);                       // 4 KB
  float* consts = (float*)(ws + 266240);                    // 32 B

  const int E = in_sizes[6];  // 100000; EB=16 divides exactly (6250 blocks)

  precomp_pack<<<256, 256, 0, stream>>>(Wq, Wk, Bqsw, Bksw);
  precomp_b<<<1, 256, 0, stream>>>(Wv, bv, Wo, bo, wvo, consts);
  fused_main<<<E / EB, 256, 0, stream>>>(h_i, evol, evt, var_i, var_j, ct, td, Wu, bu,
                                         bq, bk, Bqsw, Bksw, wvo, consts, out);
}

// Round 8
// 327.418 us; speedup vs baseline: 2.3157x; 1.0628x over previous
//
#include <hip/hip_runtime.h>
#include <cstdint>
#include <cstddef>

#define DIM 256
#define NH 4
#define W 8
#define EB 16
#define SCALE 0.125f

typedef __bf16 bf16x8 __attribute__((ext_vector_type(8)));
typedef float f32x4 __attribute__((ext_vector_type(4)));
typedef unsigned short u16x4 __attribute__((ext_vector_type(4)));

__device__ __forceinline__ f32x4 ld4(const float* p) { return *(const f32x4*)p; }
__device__ __forceinline__ f32x4 ld4_nt(const float* p) {
  return __builtin_nontemporal_load((const f32x4*)p);
}
__device__ __forceinline__ float b2f(unsigned short u) {
  unsigned int x = ((unsigned int)u) << 16;
  return __builtin_bit_cast(float, x);
}
__device__ __forceinline__ unsigned short f2b(float f) {
  __bf16 b = (__bf16)f;
  return __builtin_bit_cast(unsigned short, b);
}

// ---------------------------------------------------------------------------
// Pack Wq (x SCALE) and Wk into MFMA-B-fragment bf16 layouts (pure permute):
//  Bqsw [kt 8][nt 16][lane 64][j 8]: B[k][qcol], k=kt*32+(lane>>4)*8+j,
//       qcol=nt*16+(lane&15), val=SCALE*Wq[qcol][k]
//  Bksw [n 4][kt 2][nt 16][lane 64][j 8]: per-head B2[kk][b], kk=kt*32+...,
//       b=nt*16+(lane&15), val=Wk[n*64+kk][b]
// ---------------------------------------------------------------------------
__global__ void precomp_pack(const float* __restrict__ Wq, const float* __restrict__ Wk,
                             unsigned short* __restrict__ Bqsw,
                             unsigned short* __restrict__ Bksw) {
  int i = blockIdx.x * 256 + threadIdx.x;   // 0..65535
  int j = i & 7, lane = (i >> 3) & 63, nt = (i >> 9) & 15;
  int col15 = lane & 15, kg = lane >> 4;
  int kt = i >> 13;                          // 0..7
  Bqsw[i] = f2b(SCALE * Wq[(nt * 16 + col15) * 256 + kt * 32 + kg * 8 + j]);
  int kt2 = (i >> 13) & 1, n = i >> 14;
  Bksw[i] = f2b(Wk[(n * 64 + kt2 * 32 + kg * 8 + j) * 256 + nt * 16 + col15]);
}

// ---------------------------------------------------------------------------
// wvo[n][256] = Wv_n^T Wo_n (f32), consts[0] = bo + bv.Wo
// ---------------------------------------------------------------------------
__global__ void precomp_b(const float* __restrict__ Wv, const float* __restrict__ bv,
                          const float* __restrict__ Wo, const float* __restrict__ bo,
                          float* __restrict__ wvo, float* __restrict__ consts) {
  int t = threadIdx.x;
  for (int col = t; col < 1024; col += 256) {
    int n = col >> 8, b = col & 255;
    float sw = 0.f;
#pragma unroll 8
    for (int d = 0; d < 64; ++d)
      sw += Wv[(n * 64 + d) * 256 + b] * Wo[n * 64 + d];
    wvo[col] = sw;
  }
  if (t == 0) {
    float s = bo[0];
    for (int d = 0; d < 256; ++d) s += bv[d] * Wo[d];
    consts[0] = s;
  }
}

// ---------------------------------------------------------------------------
// Fused main kernel. Phase 1 uses the rank-64 factorization:
//   GEMM1: q = SCALE*(h@Wq^T + bq)  (wave n owns q-cols [64n,64n+64))
//   q -> small LDS bounce (overlaid on ev_lds, intra-wave) -> A-frags
//   r_n = q_n . bk_n  (in-register dot, absorbs all bias terms)
//   GEMM2: t_n = q_n @ Wk_n rows    (K=64, N=256) -> t_lds (bf16)
// Phase 2: raw-barrier pipelined ev staging, FOUR chunks ahead in registers
//   (ev chunks 0-1 issued at kernel top, hidden under phase 1).
// Phase 3: var means prefetched at chunk 12, combine heads, sigmoid.
// ---------------------------------------------------------------------------
__global__ __launch_bounds__(256, 3) void fused_main(
    const float* __restrict__ h_i, const float* __restrict__ evol,
    const float* __restrict__ evt, const float* __restrict__ var_i,
    const float* __restrict__ var_j, const float* __restrict__ cur_t,
    const float* __restrict__ tdp, const float* __restrict__ Wu,
    const float* __restrict__ bup, const float* __restrict__ bq,
    const float* __restrict__ bk, const unsigned short* __restrict__ Bqsw,
    const unsigned short* __restrict__ Bksw, const float* __restrict__ wvo,
    const float* __restrict__ consts, float* __restrict__ out) {

  __shared__ unsigned short t_lds[EB * 1024];   // 32 KB  (bf16 bits)
  __shared__ float ev_lds[2][2048];             // 16 KB  (1-edge dbuf; q overlay)
  __shared__ float part_lds[EB][NH];            // 256 B
  __shared__ float r_lds[EB][NH];               // 256 B

  const int tid = threadIdx.x;
  const int wid = tid >> 6;        // wave index == head index
  const int lane = tid & 63;
  const int e0 = blockIdx.x * EB;

  const int col15 = lane & 15;     // D-col / A-row index
  const int kg = lane >> 4;        // k-group

  // ---- ev chunks 0,1 issued NOW: latency hides under all of phase 1 ----
  const float* evg = evol + (size_t)e0 * (W * DIM);
  f32x4 rA[4], rB[4];
  rA[0] = ld4_nt(evg + tid * 4);
  rB[0] = ld4_nt(evg + 1024 + tid * 4);
  rA[1] = ld4_nt(evg + 2048 + tid * 4);
  rB[1] = ld4_nt(evg + 2048 + 1024 + tid * 4);

  // ---------------- phase 1a: GEMM1 q = SCALE*(h @ Wq^T + bq) ----------------
  f32x4 zero4 = {0.f, 0.f, 0.f, 0.f};
  f32x4 qacc[4];
#pragma unroll
  for (int i = 0; i < 4; ++i) qacc[i] = zero4;

  const float* hrow = h_i + (size_t)(e0 + col15) * DIM + kg * 8;
  const bf16x8* bq_b = (const bf16x8*)Bqsw;

#pragma unroll
  for (int ks = 0; ks < 8; ++ks) {
    f32x4 a0 = ld4(hrow + ks * 32);
    f32x4 a1 = ld4(hrow + ks * 32 + 4);
    bf16x8 af;
#pragma unroll
    for (int j = 0; j < 4; ++j) { af[j] = (__bf16)a0[j]; af[j + 4] = (__bf16)a1[j]; }
    const bf16x8* bb = bq_b + (size_t)(ks * 16 + wid * 4) * 64 + lane;
#pragma unroll
    for (int ntl = 0; ntl < 4; ++ntl)
      qacc[ntl] = __builtin_amdgcn_mfma_f32_16x16x32_bf16(af, bb[(size_t)ntl * 64], qacc[ntl], 0, 0, 0);
  }

  // q -> LDS bounce (row stride 144 B = conflict-free), + SCALE*bq
  char* qregion = (char*)ev_lds + wid * 2304;
#pragma unroll
  for (int ntl = 0; ntl < 4; ++ntl) {
    float bqv = SCALE * bq[wid * 64 + ntl * 16 + col15];
#pragma unroll
    for (int r = 0; r < 4; ++r)
      *(unsigned short*)(qregion + (kg * 4 + r) * 144 + (ntl * 16 + col15) * 2) =
          f2b(qacc[ntl][r] + bqv);
  }
  asm volatile("s_waitcnt lgkmcnt(0)" ::: "memory");

  // A-frags for GEMM2: qa[kt] = q[edge=col15][kt*32 + kg*8 .. +8]
  bf16x8 qa[2];
  qa[0] = *(const bf16x8*)(qregion + col15 * 144 + kg * 16);
  qa[1] = *(const bf16x8*)(qregion + col15 * 144 + 64 + kg * 16);

  // r[edge][n] = q_n . bk_n   (zero-valued here; handled generally)
  {
    float rp = 0.f;
#pragma unroll
    for (int kt = 0; kt < 2; ++kt) {
      f32x4 b0 = ld4(bk + wid * 64 + kt * 32 + kg * 8);
      f32x4 b1 = ld4(bk + wid * 64 + kt * 32 + kg * 8 + 4);
#pragma unroll
      for (int j = 0; j < 4; ++j)
        rp += (float)qa[kt][j] * b0[j] + (float)qa[kt][j + 4] * b1[j];
    }
    rp += __shfl_xor(rp, 16);
    rp += __shfl_xor(rp, 32);
    if (lane < 16) r_lds[lane][wid] = rp;
  }

  // ---------------- phase 1b: GEMM2 t_n = q_n @ Wk_n ----------------
  f32x4 tacc[16];
#pragma unroll
  for (int i = 0; i < 16; ++i) tacc[i] = zero4;
  const bf16x8* bk_b = (const bf16x8*)Bksw;
#pragma unroll
  for (int kt = 0; kt < 2; ++kt) {
    const bf16x8* bb = bk_b + (size_t)((wid * 2 + kt) * 16) * 64 + lane;
#pragma unroll
    for (int nt = 0; nt < 16; ++nt)
      tacc[nt] = __builtin_amdgcn_mfma_f32_16x16x32_bf16(qa[kt], bb[(size_t)nt * 64], tacc[nt], 0, 0, 0);
  }
  // D: edge = kg*4 + r, dim = wid*256 + nt*16 + col15  (intra-wave for phase 2)
#pragma unroll
  for (int nt = 0; nt < 16; ++nt) {
    int dim = wid * 256 + nt * 16 + col15;
#pragma unroll
    for (int r = 0; r < 4; ++r)
      t_lds[(kg * 4 + r) * 1024 + dim] = f2b(tacc[nt][r]);
  }

  // epilogue constants/operands (L2-hot)
  const int c = lane & 7;          // dim-chunk index
  const int oct = lane >> 3;       // window index
  f32x4 wvoR[8], wuR[8];
#pragma unroll
  for (int k = 0; k < 8; ++k) {
    wvoR[k] = ld4(wvo + wid * 256 + k * 32 + c * 4);
    wuR[k] = ld4(Wu + k * 32 + c * 4);
  }
  const float tdec = fabsf(tdp[0]);
  const float buv = bup[0];

  // ---------------- staging prologue ----------------
  // issue chunks 2,3; after q-overlay is dead, write chunk 0 to LDS slot 0.
  rA[2] = ld4_nt(evg + 2 * 2048 + tid * 4);
  rB[2] = ld4_nt(evg + 2 * 2048 + 1024 + tid * 4);
  rA[3] = ld4_nt(evg + 3 * 2048 + tid * 4);
  rB[3] = ld4_nt(evg + 3 * 2048 + 1024 + tid * 4);
  __builtin_amdgcn_s_barrier();      // all waves done reading q overlay
  __builtin_amdgcn_sched_barrier(0);
  *(f32x4*)&ev_lds[0][tid * 4] = rA[0];
  *(f32x4*)&ev_lds[0][1024 + tid * 4] = rB[0];
  asm volatile("s_waitcnt lgkmcnt(0)" ::: "memory");
  __builtin_amdgcn_s_barrier();      // buf0 ready
  __builtin_amdgcn_sched_barrier(0);

  // phase-3 var prefetch registers (loaded at chunk 12; short live range)
  f32x4 pvi[4], pvj[4];

  // ---------------- phase 2: depth-4 pipelined chunk loop ----------------
#pragma unroll
  for (int m = 0; m < EB; ++m) {
    const int sl = m & 1, sn = (m + 1) & 1;
    if (m + 4 < EB) {                 // issue chunk m+4 into reg slot (m&3)
      rA[m & 3] = ld4_nt(evg + (size_t)(m + 4) * 2048 + tid * 4);
      rB[m & 3] = ld4_nt(evg + (size_t)(m + 4) * 2048 + 1024 + tid * 4);
    }
    if (m == EB - 4) {                // phase-3 var prefetch (tail hiding)
#pragma unroll
      for (int e = 0; e < 4; ++e) {
        pvi[e] = ld4_nt(var_i + (size_t)(e0 + wid * 4 + e) * DIM + lane * 4);
        pvj[e] = ld4_nt(var_j + (size_t)(e0 + wid * 4 + e) * DIM + lane * 4);
      }
    }
    if (m + 1 < EB) {                 // write chunk m+1 (counted vmcnt wait)
      *(f32x4*)&ev_lds[sn][tid * 4] = rA[(m + 1) & 3];
      *(f32x4*)&ev_lds[sn][1024 + tid * 4] = rB[(m + 1) & 3];
    }
    {
      const float* evb = &ev_lds[sl][oct * 256 + c * 4];
      const unsigned short* tb = &t_lds[m * 1024 + wid * 256 + c * 4];
      float dt = 0.f, dg = 0.f, du = 0.f;
#pragma unroll
      for (int k = 0; k < 8; ++k) {
        f32x4 evv = ld4(evb + k * 32);
        u16x4 tu = *(const u16x4*)(tb + k * 32);
        dt += evv[0] * b2f(tu[0]) + evv[1] * b2f(tu[1]) + evv[2] * b2f(tu[2]) + evv[3] * b2f(tu[3]);
        dg += evv[0] * wvoR[k][0] + evv[1] * wvoR[k][1] + evv[2] * wvoR[k][2] + evv[3] * wvoR[k][3];
        du += evv[0] * wuR[k][0] + evv[1] * wuR[k][1] + evv[2] * wuR[k][2] + evv[3] * wuR[k][3];
      }
#pragma unroll
      for (int s = 1; s < 8; s <<= 1) {
        dt += __shfl_xor(dt, s);
        dg += __shfl_xor(dg, s);
        du += __shfl_xor(du, s);
      }
      float tev = evt[(size_t)(e0 + m) * W + oct];
      float tbias = -tdec * fmaxf(cur_t[e0 + m] - tev, 0.f);
      float unc = 1.f / (1.f + __expf(-(du + buv)));
      float logit = (dt + r_lds[m][wid] + tbias) * unc;
      float mx = logit;
#pragma unroll
      for (int s = 8; s < 64; s <<= 1) mx = fmaxf(mx, __shfl_xor(mx, s));
      float p = __expf(logit - mx);
      float pg = p * dg, ps = p;
#pragma unroll
      for (int s = 8; s < 64; s <<= 1) { ps += __shfl_xor(ps, s); pg += __shfl_xor(pg, s); }
      if (lane == 0) part_lds[m][wid] = pg / ps;
    }
    asm volatile("s_waitcnt lgkmcnt(0)" ::: "memory");
    __builtin_amdgcn_s_barrier();     // chunk m consumed; chunk m+1 ready
    __builtin_amdgcn_sched_barrier(0);
  }

  // ---------------- phase 3: conf + output (registers only) ----------------
  const float c0 = consts[0];
#pragma unroll
  for (int e = 0; e < 4; ++e) {
    const int m = wid * 4 + e;
    float si = pvi[e][0] + pvi[e][1] + pvi[e][2] + pvi[e][3];
    float sj = pvj[e][0] + pvj[e][1] + pvj[e][2] + pvj[e][3];
#pragma unroll
    for (int s = 1; s < 64; s <<= 1) { si += __shfl_xor(si, s); sj += __shfl_xor(sj, s); }
    if (lane == 0) {
      float logit = part_lds[m][0] + part_lds[m][1] + part_lds[m][2] + part_lds[m][3] + c0;
      float ci = 1.f / (1.f + fmaxf(sqrtf(si * (1.f / 256.f)), 1e-6f));
      float cj = 1.f / (1.f + fmaxf(sqrtf(sj * (1.f / 256.f)), 1e-6f));
      out[e0 + m] = 1.f / (1.f + __expf(-logit * ci * cj));
    }
  }
}

extern "C" void kernel_launch(void* const* d_in, const int* in_sizes, int n_in,
                              void* d_out, int out_size, void* d_ws, size_t ws_size,
                              hipStream_t stream) {
  const float* h_i = (const float*)d_in[0];
  // d_in[1] (h_j) is unused by the reference
  const float* evol = (const float*)d_in[2];
  const float* evt = (const float*)d_in[3];
  const float* var_i = (const float*)d_in[4];
  const float* var_j = (const float*)d_in[5];
  const float* ct = (const float*)d_in[6];
  const float* Wq = (const float*)d_in[7];
  const float* bq = (const float*)d_in[8];
  const float* Wk = (const float*)d_in[9];
  const float* bk = (const float*)d_in[10];
  const float* Wv = (const float*)d_in[11];
  const float* bv = (const float*)d_in[12];
  const float* td = (const float*)d_in[13];
  const float* Wu = (const float*)d_in[14];
  const float* bu = (const float*)d_in[15];
  const float* Wo = (const float*)d_in[16];
  const float* bo = (const float*)d_in[17];
  float* out = (float*)d_out;

  char* ws = (char*)d_ws;
  unsigned short* Bqsw = (unsigned short*)ws;               // 128 KB
  unsigned short* Bksw = (unsigned short*)(ws + 131072);    // 128 KB
  float* wvo = (float*)(ws + 262144);                       // 4 KB
  float* consts = (float*)(ws + 266240);                    // 32 B

  const int E = in_sizes[6];  // 100000; EB=16 divides exactly (6250 blocks)

  precomp_pack<<<256, 256, 0, stream>>>(Wq, Wk, Bqsw, Bksw);
  precomp_b<<<1, 256, 0, stream>>>(Wv, bv, Wo, bo, wvo, consts);
  fused_main<<<E / EB, 256, 0, stream>>>(h_i, evol, evt, var_i, var_j, ct, td, Wu, bu,
                                         bq, bk, Bqsw, Bksw, wvo, consts, out);
}

// Round 9
// 293.448 us; speedup vs baseline: 2.5838x; 1.1158x over previous
//
#include <hip/hip_runtime.h>
#include <cstdint>
#include <cstddef>

#define DIM 256
#define NH 4
#define W 8
#define EB 16
#define SCALE 0.125f

typedef __bf16 bf16x8 __attribute__((ext_vector_type(8)));
typedef float f32x4 __attribute__((ext_vector_type(4)));
typedef unsigned short u16x4 __attribute__((ext_vector_type(4)));

__device__ __forceinline__ f32x4 ld4(const float* p) { return *(const f32x4*)p; }
__device__ __forceinline__ f32x4 ld4_nt(const float* p) {
  return __builtin_nontemporal_load((const f32x4*)p);
}
__device__ __forceinline__ float b2f(unsigned short u) {
  unsigned int x = ((unsigned int)u) << 16;
  return __builtin_bit_cast(float, x);
}
__device__ __forceinline__ unsigned short f2b(float f) {
  __bf16 b = (__bf16)f;
  return __builtin_bit_cast(unsigned short, b);
}

// ---------------------------------------------------------------------------
// Pack Wq (x SCALE) and Wk into MFMA-B-fragment bf16 layouts (pure permute):
//  Bqsw [kt 8][nt 16][lane 64][j 8]: B[k][qcol], k=kt*32+(lane>>4)*8+j,
//       qcol=nt*16+(lane&15), val=SCALE*Wq[qcol][k]
//  Bksw [n 4][kt 2][nt 16][lane 64][j 8]: per-head B2[kk][b], kk=kt*32+...,
//       b=nt*16+(lane&15), val=Wk[n*64+kk][b]
// ---------------------------------------------------------------------------
__global__ void precomp_pack(const float* __restrict__ Wq, const float* __restrict__ Wk,
                             unsigned short* __restrict__ Bqsw,
                             unsigned short* __restrict__ Bksw) {
  int i = blockIdx.x * 256 + threadIdx.x;   // 0..65535
  int j = i & 7, lane = (i >> 3) & 63, nt = (i >> 9) & 15;
  int col15 = lane & 15, kg = lane >> 4;
  int kt = i >> 13;                          // 0..7
  Bqsw[i] = f2b(SCALE * Wq[(nt * 16 + col15) * 256 + kt * 32 + kg * 8 + j]);
  int kt2 = (i >> 13) & 1, n = i >> 14;
  Bksw[i] = f2b(Wk[(n * 64 + kt2 * 32 + kg * 8 + j) * 256 + nt * 16 + col15]);
}

// ---------------------------------------------------------------------------
// wvo[n][256] = Wv_n^T Wo_n (f32), consts[0] = bo + bv.Wo
// ---------------------------------------------------------------------------
__global__ void precomp_b(const float* __restrict__ Wv, const float* __restrict__ bv,
                          const float* __restrict__ Wo, const float* __restrict__ bo,
                          float* __restrict__ wvo, float* __restrict__ consts) {
  int t = threadIdx.x;
  for (int col = t; col < 1024; col += 256) {
    int n = col >> 8, b = col & 255;
    float sw = 0.f;
#pragma unroll 8
    for (int d = 0; d < 64; ++d)
      sw += Wv[(n * 64 + d) * 256 + b] * Wo[n * 64 + d];
    wvo[col] = sw;
  }
  if (t == 0) {
    float s = bo[0];
    for (int d = 0; d < 256; ++d) s += bv[d] * Wo[d];
    consts[0] = s;
  }
}

// ---------------------------------------------------------------------------
// Fused main kernel.
//  phase 1 (rank-64): GEMM1 q = SCALE*(h@Wq^T+bq); q->q_lds (intra-wave);
//           r = q.bk -> r_lds; GEMM2 t_n = q_n@Wk_n -> t_lds (bf16).
//  ONE barrier (lgkmcnt only; global loads stay in flight).
//  phase 2: wave owns 4 edges end-to-end, all heads in-lane. ev read DIRECTLY
//           from global (2 edges in flight, edge 0 issued at kernel top),
//           t/wvo/Wu from LDS (broadcast reads, conflict-free). Softmax +
//           head combine + conf + sigmoid per edge, no further barriers.
// ---------------------------------------------------------------------------
__global__ __launch_bounds__(256, 3) void fused_main(
    const float* __restrict__ h_i, const float* __restrict__ evol,
    const float* __restrict__ evt, const float* __restrict__ var_i,
    const float* __restrict__ var_j, const float* __restrict__ cur_t,
    const float* __restrict__ tdp, const float* __restrict__ Wu,
    const float* __restrict__ bup, const float* __restrict__ bq,
    const float* __restrict__ bk, const unsigned short* __restrict__ Bqsw,
    const unsigned short* __restrict__ Bksw, const float* __restrict__ wvo,
    const float* __restrict__ consts, float* __restrict__ out) {

  __shared__ unsigned short t_lds[EB * 1024];   // 32 KB (bf16 bits, [m][n*256+d])
  __shared__ unsigned short q_lds[4 * 1152];    // 9 KB  (per-wave q bounce)
  __shared__ float wvou_lds[1280];              // 5 KB  (wvo[1024] | Wu[256])
  __shared__ float r_lds[EB][NH];               // 256 B

  const int tid = threadIdx.x;
  const int wid = tid >> 6;        // wave index
  const int lane = tid & 63;
  const int e0 = blockIdx.x * EB;
  const int eb = e0 + wid * 4;     // this wave's first edge

  const int col15 = lane & 15;
  const int kg = lane >> 4;
  const int oct = lane >> 3;       // window index (phase 2)
  const int c = lane & 7;          // dim-chunk index (phase 2)

#define EV_ISSUE(EV, el) {                                                     \
    const float* _p = evol + (size_t)(eb + (el)) * 2048 + oct * 256 + c * 4;   \
    _Pragma("unroll") for (int k = 0; k < 8; ++k) EV[k] = ld4_nt(_p + k * 32); }

  // ---- edge 0 ev issued NOW: latency hides under all of phase 1 ----
  f32x4 evA[8], evB[8];
  EV_ISSUE(evA, 0)

  // wvo/Wu -> LDS (block-wide; visible after the single barrier)
  for (int i = tid; i < 1280; i += 256)
    wvou_lds[i] = (i < 1024) ? wvo[i] : Wu[i - 1024];

  // ---------------- phase 1a: GEMM1 q = SCALE*(h @ Wq^T + bq) ----------------
  f32x4 zero4 = {0.f, 0.f, 0.f, 0.f};
  f32x4 qacc[4];
#pragma unroll
  for (int i = 0; i < 4; ++i) qacc[i] = zero4;

  const float* hrow = h_i + (size_t)(e0 + col15) * DIM + kg * 8;
  const bf16x8* bq_b = (const bf16x8*)Bqsw;

#pragma unroll
  for (int ks = 0; ks < 8; ++ks) {
    f32x4 a0 = ld4(hrow + ks * 32);
    f32x4 a1 = ld4(hrow + ks * 32 + 4);
    bf16x8 af;
#pragma unroll
    for (int j = 0; j < 4; ++j) { af[j] = (__bf16)a0[j]; af[j + 4] = (__bf16)a1[j]; }
    const bf16x8* bb = bq_b + (size_t)(ks * 16 + wid * 4) * 64 + lane;
#pragma unroll
    for (int ntl = 0; ntl < 4; ++ntl)
      qacc[ntl] = __builtin_amdgcn_mfma_f32_16x16x32_bf16(af, bb[(size_t)ntl * 64], qacc[ntl], 0, 0, 0);
  }

  // q -> LDS bounce (row stride 144 B), + SCALE*bq   [intra-wave only]
  char* qregion = (char*)q_lds + wid * 2304;
#pragma unroll
  for (int ntl = 0; ntl < 4; ++ntl) {
    float bqv = SCALE * bq[wid * 64 + ntl * 16 + col15];
#pragma unroll
    for (int r = 0; r < 4; ++r)
      *(unsigned short*)(qregion + (kg * 4 + r) * 144 + (ntl * 16 + col15) * 2) =
          f2b(qacc[ntl][r] + bqv);
  }
  asm volatile("s_waitcnt lgkmcnt(0)" ::: "memory");

  bf16x8 qa[2];
  qa[0] = *(const bf16x8*)(qregion + col15 * 144 + kg * 16);
  qa[1] = *(const bf16x8*)(qregion + col15 * 144 + 64 + kg * 16);

  // r[edge][n] = q_n . bk_n   (zero-valued here; handled generally)
  {
    float rp = 0.f;
#pragma unroll
    for (int kt = 0; kt < 2; ++kt) {
      f32x4 b0 = ld4(bk + wid * 64 + kt * 32 + kg * 8);
      f32x4 b1 = ld4(bk + wid * 64 + kt * 32 + kg * 8 + 4);
#pragma unroll
      for (int j = 0; j < 4; ++j)
        rp += (float)qa[kt][j] * b0[j] + (float)qa[kt][j + 4] * b1[j];
    }
    rp += __shfl_xor(rp, 16);
    rp += __shfl_xor(rp, 32);
    if (lane < 16) r_lds[lane][wid] = rp;
  }

  // ---------------- phase 1b: GEMM2 t_n = q_n @ Wk_n ----------------
  f32x4 tacc[16];
#pragma unroll
  for (int i = 0; i < 16; ++i) tacc[i] = zero4;
  const bf16x8* bk_b = (const bf16x8*)Bksw;
#pragma unroll
  for (int kt = 0; kt < 2; ++kt) {
    const bf16x8* bb = bk_b + (size_t)((wid * 2 + kt) * 16) * 64 + lane;
#pragma unroll
    for (int nt = 0; nt < 16; ++nt)
      tacc[nt] = __builtin_amdgcn_mfma_f32_16x16x32_bf16(qa[kt], bb[(size_t)nt * 64], tacc[nt], 0, 0, 0);
  }
  // D: edge = kg*4 + r, dim = wid*256 + nt*16 + col15
#pragma unroll
  for (int nt = 0; nt < 16; ++nt) {
    int dim = wid * 256 + nt * 16 + col15;
#pragma unroll
    for (int r = 0; r < 4; ++r)
      t_lds[(kg * 4 + r) * 1024 + dim] = f2b(tacc[nt][r]);
  }

  // ---- edge 1 ev issued before the barrier (stays in flight across it) ----
  EV_ISSUE(evB, 1)

  // ---------------- the ONE barrier (t_lds/r_lds/wvou cross-wave) -----------
  asm volatile("s_waitcnt lgkmcnt(0)" ::: "memory");
  __builtin_amdgcn_s_barrier();
  __builtin_amdgcn_sched_barrier(0);

  // ---------------- phase 2: per-wave 4 edges, all heads in-lane ------------
  const float tdec = fabsf(tdp[0]);
  const float buv = bup[0];
  const float c0 = consts[0];

#define EV_COMPUTE(EV, el) {                                                   \
    const int em = wid * 4 + (el);                                             \
    const int e = e0 + em;                                                     \
    f32x4 vi = ld4_nt(var_i + (size_t)e * DIM + lane * 4);                     \
    f32x4 vj = ld4_nt(var_j + (size_t)e * DIM + lane * 4);                     \
    float tev = evt[(size_t)e * W + oct];                                      \
    float ctv = cur_t[e];                                                      \
    float dt[4] = {0.f, 0.f, 0.f, 0.f}, dg[4] = {0.f, 0.f, 0.f, 0.f};          \
    float du = 0.f;                                                            \
    _Pragma("unroll") for (int n = 0; n < 4; ++n) {                            \
      const unsigned short* tb = &t_lds[em * 1024 + n * 256 + c * 4];          \
      const float* wb = &wvou_lds[n * 256 + c * 4];                            \
      _Pragma("unroll") for (int k = 0; k < 8; ++k) {                          \
        u16x4 tu = *(const u16x4*)(tb + k * 32);                               \
        f32x4 wv = *(const f32x4*)(wb + k * 32);                               \
        _Pragma("unroll") for (int j = 0; j < 4; ++j) {                        \
          dt[n] += EV[k][j] * b2f(tu[j]);                                      \
          dg[n] += EV[k][j] * wv[j];                                           \
        } } }                                                                  \
    _Pragma("unroll") for (int k = 0; k < 8; ++k) {                            \
      f32x4 wu = *(const f32x4*)(&wvou_lds[1024 + k * 32 + c * 4]);            \
      _Pragma("unroll") for (int j = 0; j < 4; ++j) du += EV[k][j] * wu[j];    \
    }                                                                          \
    _Pragma("unroll") for (int s = 1; s < 8; s <<= 1) {                        \
      _Pragma("unroll") for (int n = 0; n < 4; ++n) {                          \
        dt[n] += __shfl_xor(dt[n], s);                                         \
        dg[n] += __shfl_xor(dg[n], s);                                         \
      }                                                                        \
      du += __shfl_xor(du, s);                                                 \
    }                                                                          \
    float tbias = -tdec * fmaxf(ctv - tev, 0.f);                               \
    float unc = 1.f / (1.f + __expf(-(du + buv)));                             \
    float L[4], mx[4];                                                         \
    _Pragma("unroll") for (int n = 0; n < 4; ++n) {                            \
      L[n] = (dt[n] + r_lds[em][n] + tbias) * unc;                             \
      mx[n] = L[n];                                                            \
    }                                                                          \
    _Pragma("unroll") for (int s = 8; s < 64; s <<= 1)                         \
      _Pragma("unroll") for (int n = 0; n < 4; ++n)                            \
        mx[n] = fmaxf(mx[n], __shfl_xor(mx[n], s));                            \
    float ps[4], pg[4];                                                        \
    _Pragma("unroll") for (int n = 0; n < 4; ++n) {                            \
      float p = __expf(L[n] - mx[n]);                                          \
      ps[n] = p;                                                               \
      pg[n] = p * dg[n];                                                       \
    }                                                                          \
    _Pragma("unroll") for (int s = 8; s < 64; s <<= 1)                         \
      _Pragma("unroll") for (int n = 0; n < 4; ++n) {                          \
        ps[n] += __shfl_xor(ps[n], s);                                         \
        pg[n] += __shfl_xor(pg[n], s);                                         \
      }                                                                        \
    float logit = pg[0] / ps[0] + pg[1] / ps[1] + pg[2] / ps[2] + pg[3] / ps[3] + c0; \
    float si = vi[0] + vi[1] + vi[2] + vi[3];                                  \
    float sj = vj[0] + vj[1] + vj[2] + vj[3];                                  \
    _Pragma("unroll") for (int s = 1; s < 64; s <<= 1) {                       \
      si += __shfl_xor(si, s);                                                 \
      sj += __shfl_xor(sj, s);                                                 \
    }                                                                          \
    if (lane == 0) {                                                           \
      float ci = 1.f / (1.f + fmaxf(sqrtf(si * (1.f / 256.f)), 1e-6f));        \
      float cj = 1.f / (1.f + fmaxf(sqrtf(sj * (1.f / 256.f)), 1e-6f));        \
      out[e] = 1.f / (1.f + __expf(-logit * ci * cj));                         \
    } }

  EV_COMPUTE(evA, 0)
  EV_ISSUE(evA, 2)
  EV_COMPUTE(evB, 1)
  EV_ISSUE(evB, 3)
  EV_COMPUTE(evA, 2)
  EV_COMPUTE(evB, 3)

#undef EV_ISSUE
#undef EV_COMPUTE
}

extern "C" void kernel_launch(void* const* d_in, const int* in_sizes, int n_in,
                              void* d_out, int out_size, void* d_ws, size_t ws_size,
                              hipStream_t stream) {
  const float* h_i = (const float*)d_in[0];
  // d_in[1] (h_j) is unused by the reference
  const float* evol = (const float*)d_in[2];
  const float* evt = (const float*)d_in[3];
  const float* var_i = (const float*)d_in[4];
  const float* var_j = (const float*)d_in[5];
  const float* ct = (const float*)d_in[6];
  const float* Wq = (const float*)d_in[7];
  const float* bq = (const float*)d_in[8];
  const float* Wk = (const float*)d_in[9];
  const float* bk = (const float*)d_in[10];
  const float* Wv = (const float*)d_in[11];
  const float* bv = (const float*)d_in[12];
  const float* td = (const float*)d_in[13];
  const float* Wu = (const float*)d_in[14];
  const float* bu = (const float*)d_in[15];
  const float* Wo = (const float*)d_in[16];
  const float* bo = (const float*)d_in[17];
  float* out = (float*)d_out;

  char* ws = (char*)d_ws;
  unsigned short* Bqsw = (unsigned short*)ws;               // 128 KB
  unsigned short* Bksw = (unsigned short*)(ws + 131072);    // 128 KB
  float* wvo = (float*)(ws + 262144);                       // 4 KB
  float* consts = (float*)(ws + 266240);                    // 32 B

  const int E = in_sizes[6];  // 100000; EB=16 divides exactly (6250 blocks)

  precomp_pack<<<256, 256, 0, stream>>>(Wq, Wk, Bqsw, Bksw);
  precomp_b<<<1, 256, 0, stream>>>(Wv, bv, Wo, bo, wvo, consts);
  fused_main<<<E / EB, 256, 0, stream>>>(h_i, evol, evt, var_i, var_j, ct, td, Wu, bu,
                                         bq, bk, Bqsw, Bksw, wvo, consts, out);
}